// Round 3
// baseline (2693.743 us; speedup 1.0000x reference)
//
#include <hip/hip_runtime.h>
#include <hip/hip_bf16.h>

#define N_NODES 4096
#define IN_DIM  256
#define HIDDEN  512
#define CLASSES 256
#define HEADS   4
#define HD      64
#define NEDGE   131072
#define NMASK   (N_NODES - 1)

// ---------------------------------------------------------------------------
// Small utility kernels
// ---------------------------------------------------------------------------
__global__ void zero_k(float* __restrict__ p, int n) {
    int i = blockIdx.x * 256 + threadIdx.x;
    if (i < n) p[i] = 0.0f;
}

__global__ void deg_count_k(const int* __restrict__ dst, float* __restrict__ deg) {
    int i = blockIdx.x * 256 + threadIdx.x;
    if (i < NEDGE) atomicAdd(&deg[dst[i] & NMASK], 1.0f);
}

__global__ void make_dinv_k(const float* __restrict__ deg, float* __restrict__ dinv) {
    int i = blockIdx.x * 256 + threadIdx.x;
    if (i < N_NODES) dinv[i] = 1.0f / sqrtf(deg[i] + 1.0f);  // +1 self-loop
}

// out[n][f] = h[n][f] * dinv[n]^2   (self-loop message; zero-initializes out)
__global__ void agg_init_k(const float* __restrict__ h, const float* __restrict__ dinv,
                           float* __restrict__ out) {
    int i = blockIdx.x * 256 + threadIdx.x;     // over N*128 (float4)
    int n = i >> 7;
    float w = dinv[n]; w *= w;
    float4 v = ((const float4*)h)[i];
    v.x *= w; v.y *= w; v.z *= w; v.w *= w;
    ((float4*)out)[i] = v;
}

// out[dst] += h[src] * dinv[src]*dinv[dst]   (E edges x 512 features, float4)
__global__ void agg_edges_k(const float* __restrict__ h, const int* __restrict__ src,
                            const int* __restrict__ dst, const float* __restrict__ dinv,
                            float* __restrict__ out) {
    int i = blockIdx.x * 256 + threadIdx.x;     // over E*128
    int e = i >> 7;
    int c = i & 127;
    if (e >= NEDGE) return;
    int s = src[e] & NMASK, d = dst[e] & NMASK;
    float w = dinv[s] * dinv[d];
    float4 v = *(const float4*)(h + ((size_t)s << 9) + (c << 2));
    float* op = out + ((size_t)d << 9) + (c << 2);
    atomicAdd(op + 0, v.x * w);
    atomicAdd(op + 1, v.y * w);
    atomicAdd(op + 2, v.z * w);
    atomicAdd(op + 3, v.w * w);
}

// x = relu(x + b[col]) in place; C4 = cols/4
__global__ void bias_relu_k(float* __restrict__ x, const float* __restrict__ b,
                            int total4, int C4) {
    int i = blockIdx.x * 256 + threadIdx.x;
    if (i >= total4) return;
    int c4 = (i % C4) * 4;
    float4 v = ((float4*)x)[i];
    v.x = fmaxf(v.x + b[c4 + 0], 0.f);
    v.y = fmaxf(v.y + b[c4 + 1], 0.f);
    v.z = fmaxf(v.z + b[c4 + 2], 0.f);
    v.w = fmaxf(v.w + b[c4 + 3], 0.f);
    ((float4*)x)[i] = v;
}

// ---------------------------------------------------------------------------
// fp32 tiled GEMM: C[M,N] = A[M,K] @ (TRANSB ? B[N,K]^T : B[K,N])
//   optional +bias[col], +srcadd[M,N], relu.  M,N % 64 == 0, K % 16 == 0.
// 256 threads, 64x64 tile, 4x4 micro-tile per thread.
// ---------------------------------------------------------------------------
template<bool TRANSB, bool ADDBIAS, bool ADDSRC, bool RELU>
__global__ __launch_bounds__(256) void gemm_k(
    const float* __restrict__ A, const float* __restrict__ B,
    const float* __restrict__ bias, const float* __restrict__ srcadd,
    float* __restrict__ C, int M, int N, int K)
{
    __shared__ float As[16][68];
    __shared__ float Bs[16][68];
    const int tid = threadIdx.x;
    const int tx = tid & 15, ty = tid >> 4;
    const int m0 = blockIdx.x * 64, n0 = blockIdx.y * 64;
    const int lr  = tid >> 2;          // 0..63
    const int lc4 = (tid & 3) * 4;     // 0,4,8,12

    float acc[4][4] = {};

    for (int k0 = 0; k0 < K; k0 += 16) {
        float4 av = *(const float4*)(A + (size_t)(m0 + lr) * K + k0 + lc4);
        float4 bv;
        int bkk = 0, bc = 0;
        if (TRANSB) {
            bv = *(const float4*)(B + (size_t)(n0 + lr) * K + k0 + lc4);
        } else {
            bkk = tid >> 4;             // 0..15
            bc  = (tid & 15) * 4;       // 0..60
            bv = *(const float4*)(B + (size_t)(k0 + bkk) * N + n0 + bc);
        }
        __syncthreads();
        As[lc4 + 0][lr] = av.x; As[lc4 + 1][lr] = av.y;
        As[lc4 + 2][lr] = av.z; As[lc4 + 3][lr] = av.w;
        if (TRANSB) {
            Bs[lc4 + 0][lr] = bv.x; Bs[lc4 + 1][lr] = bv.y;
            Bs[lc4 + 2][lr] = bv.z; Bs[lc4 + 3][lr] = bv.w;
        } else {
            *(float4*)&Bs[bkk][bc] = bv;
        }
        __syncthreads();
        #pragma unroll
        for (int kk = 0; kk < 16; ++kk) {
            float4 a = *(const float4*)&As[kk][ty * 4];
            float4 b = *(const float4*)&Bs[kk][tx * 4];
            float ar[4] = {a.x, a.y, a.z, a.w};
            float br[4] = {b.x, b.y, b.z, b.w};
            #pragma unroll
            for (int i = 0; i < 4; ++i)
                #pragma unroll
                for (int j = 0; j < 4; ++j)
                    acc[i][j] += ar[i] * br[j];
        }
    }

    #pragma unroll
    for (int i = 0; i < 4; ++i) {
        int r = m0 + ty * 4 + i;
        int c = n0 + tx * 4;
        float4 v = { acc[i][0], acc[i][1], acc[i][2], acc[i][3] };
        if (ADDBIAS) {
            v.x += bias[c + 0]; v.y += bias[c + 1];
            v.z += bias[c + 2]; v.w += bias[c + 3];
        }
        if (ADDSRC) {
            float4 sv = *(const float4*)(srcadd + (size_t)r * N + c);
            v.x += sv.x; v.y += sv.y; v.z += sv.z; v.w += sv.w;
        }
        if (RELU) {
            v.x = fmaxf(v.x, 0.f); v.y = fmaxf(v.y, 0.f);
            v.z = fmaxf(v.z, 0.f); v.w = fmaxf(v.w, 0.f);
        }
        *(float4*)(C + (size_t)r * N + c) = v;
    }
}

// ---------------------------------------------------------------------------
// Flash-style fp32 attention: 4 heads, N=4096, HD=64.
// qkv: [N, 768] (q | k | v).   out: [N, 256] (heads concatenated).
// Block = 256 threads, 64 q-rows per block, k/v tiles of 64.
// ---------------------------------------------------------------------------
__global__ __launch_bounds__(256) void attn_k(const float* __restrict__ qkv,
                                              float* __restrict__ out)
{
    __shared__ float Qs[64][68];    // Qs[d][r] (scaled)
    __shared__ float KVs[64][68];   // K phase: [d][c]; V phase: [kv][d]
    __shared__ float Ps[64][68];    // Ps[kv][r]

    const int h  = blockIdx.y;
    const int q0 = blockIdx.x * 64;
    const int tid = threadIdx.x;
    const int tx = tid & 15, ty = tid >> 4;
    const int lr  = tid >> 2;         // 0..63
    const int ld4 = (tid & 3) * 4;    // 0,4,8,12
    const float scale = 0.125f;       // 1/sqrt(64)

    {   // load Q tile transposed + scaled
        const float* qp = qkv + (size_t)(q0 + lr) * 768 + h * 64 + ld4;
        #pragma unroll
        for (int u = 0; u < 4; ++u) {
            float4 v = *(const float4*)(qp + u * 16);
            int d = ld4 + u * 16;
            Qs[d + 0][lr] = v.x * scale; Qs[d + 1][lr] = v.y * scale;
            Qs[d + 2][lr] = v.z * scale; Qs[d + 3][lr] = v.w * scale;
        }
    }

    float m[4], l[4], o[4][4];
    #pragma unroll
    for (int i = 0; i < 4; ++i) {
        m[i] = -1e30f; l[i] = 0.f;
        #pragma unroll
        for (int j = 0; j < 4; ++j) o[i][j] = 0.f;
    }

    for (int kt = 0; kt < 64; ++kt) {
        const int kv0 = kt * 64;
        // K tile -> registers
        const float* kp = qkv + (size_t)(kv0 + lr) * 768 + 256 + h * 64 + ld4;
        float4 kreg[4];
        #pragma unroll
        for (int u = 0; u < 4; ++u) kreg[u] = *(const float4*)(kp + u * 16);

        __syncthreads();   // previous PV done reading KVs/Ps (also covers Qs on kt==0)
        #pragma unroll
        for (int u = 0; u < 4; ++u) {
            int d = ld4 + u * 16;
            KVs[d + 0][lr] = kreg[u].x; KVs[d + 1][lr] = kreg[u].y;
            KVs[d + 2][lr] = kreg[u].z; KVs[d + 3][lr] = kreg[u].w;
        }
        __syncthreads();

        // S = (Q*scale) K^T
        float s[4][4] = {};
        #pragma unroll
        for (int d = 0; d < 64; ++d) {
            float4 a = *(const float4*)&Qs[d][ty * 4];
            float4 b = *(const float4*)&KVs[d][tx * 4];
            float ar[4] = {a.x, a.y, a.z, a.w};
            float br[4] = {b.x, b.y, b.z, b.w};
            #pragma unroll
            for (int i = 0; i < 4; ++i)
                #pragma unroll
                for (int j = 0; j < 4; ++j)
                    s[i][j] += ar[i] * br[j];
        }

        // V tile -> registers (before overwriting KVs)
        const float* vp = qkv + (size_t)(kv0 + lr) * 768 + 512 + h * 64 + ld4;
        float4 vreg[4];
        #pragma unroll
        for (int u = 0; u < 4; ++u) vreg[u] = *(const float4*)(vp + u * 16);

        __syncthreads();   // everyone done reading K from KVs
        #pragma unroll
        for (int u = 0; u < 4; ++u)
            *(float4*)&KVs[lr][ld4 + u * 16] = vreg[u];

        // online softmax (rows r = 4*ty+i; 16 lanes per row group share ty)
        #pragma unroll
        for (int i = 0; i < 4; ++i) {
            float mx = fmaxf(fmaxf(s[i][0], s[i][1]), fmaxf(s[i][2], s[i][3]));
            mx = fmaxf(mx, __shfl_xor(mx, 1));
            mx = fmaxf(mx, __shfl_xor(mx, 2));
            mx = fmaxf(mx, __shfl_xor(mx, 4));
            mx = fmaxf(mx, __shfl_xor(mx, 8));
            float mnew = fmaxf(m[i], mx);
            float alpha = __expf(m[i] - mnew);
            float p0 = __expf(s[i][0] - mnew);
            float p1 = __expf(s[i][1] - mnew);
            float p2 = __expf(s[i][2] - mnew);
            float p3 = __expf(s[i][3] - mnew);
            float sum = p0 + p1 + p2 + p3;
            sum += __shfl_xor(sum, 1);
            sum += __shfl_xor(sum, 2);
            sum += __shfl_xor(sum, 4);
            sum += __shfl_xor(sum, 8);
            l[i] = l[i] * alpha + sum;
            m[i] = mnew;
            #pragma unroll
            for (int j = 0; j < 4; ++j) o[i][j] *= alpha;
            Ps[tx * 4 + 0][ty * 4 + i] = p0;
            Ps[tx * 4 + 1][ty * 4 + i] = p1;
            Ps[tx * 4 + 2][ty * 4 + i] = p2;
            Ps[tx * 4 + 3][ty * 4 + i] = p3;
        }
        __syncthreads();   // Ps + V ready

        // O += P V
        #pragma unroll
        for (int kv = 0; kv < 64; ++kv) {
            float4 a = *(const float4*)&Ps[kv][ty * 4];
            float4 b = *(const float4*)&KVs[kv][tx * 4];
            float ar[4] = {a.x, a.y, a.z, a.w};
            float br[4] = {b.x, b.y, b.z, b.w};
            #pragma unroll
            for (int i = 0; i < 4; ++i)
                #pragma unroll
                for (int j = 0; j < 4; ++j)
                    o[i][j] += ar[i] * br[j];
        }
    }

    #pragma unroll
    for (int i = 0; i < 4; ++i) {
        float inv = 1.0f / l[i];
        float4 v = { o[i][0] * inv, o[i][1] * inv, o[i][2] * inv, o[i][3] * inv };
        *(float4*)(out + (size_t)(q0 + ty * 4 + i) * 256 + h * 64 + tx * 4) = v;
    }
}

// ---------------------------------------------------------------------------
// Workspace budget (floats): deg 4096 + dinv 4096 + region0 4M + xtf 1M
//   = 5,251,072 floats = ~21 MB.
// region0 is time-shared: transformer phase [qkv 3M | atto 1M],
//                         GNN phase         [bufA 2M | bufB 2M].
// d_out doubles as the x_proj intermediate (elementwise RMW in final GEMM).
// ---------------------------------------------------------------------------
extern "C" void kernel_launch(void* const* d_in, const int* in_sizes, int n_in,
                              void* d_out, int out_size, void* d_ws, size_t ws_size,
                              hipStream_t stream)
{
    const float* x          = (const float*)d_in[0];
    const int*   eidx       = (const int*)d_in[1];
    const float* gcn1_w     = (const float*)d_in[2];
    const float* gcn1_b     = (const float*)d_in[3];
    const float* gcn2_w     = (const float*)d_in[4];
    const float* gcn2_b     = (const float*)d_in[5];
    const float* lin_w      = (const float*)d_in[6];
    const float* lin_b      = (const float*)d_in[7];
    const float* in_proj_w  = (const float*)d_in[8];
    const float* in_proj_b  = (const float*)d_in[9];
    const float* out_proj_w = (const float*)d_in[10];
    const float* out_proj_b = (const float*)d_in[11];
    const float* proj_w     = (const float*)d_in[12];
    const float* proj_b     = (const float*)d_in[13];
    float* out = (float*)d_out;

    const int* esrc = eidx;
    const int* edst = eidx + NEDGE;

    float* ws   = (float*)d_ws;
    float* deg  = ws;                              // 4096
    float* dinv = deg + N_NODES;                   // 4096
    float* reg0 = dinv + N_NODES;                  // 4M floats, time-shared
    float* qkv  = reg0;                            // [4096 x 768]
    float* atto = reg0 + N_NODES * 3 * IN_DIM;     // [4096 x 256]
    float* bufA = reg0;                            // [4096 x 512]
    float* bufB = reg0 + N_NODES * HIDDEN;         // [4096 x 512]
    float* xtf  = reg0 + 4 * 1024 * 1024;          // [4096 x 256]

    // --- GCN normalization ---
    zero_k<<<(N_NODES + 255) / 256, 256, 0, stream>>>(deg, N_NODES);
    deg_count_k<<<(NEDGE + 255) / 256, 256, 0, stream>>>(edst, deg);
    make_dinv_k<<<(N_NODES + 255) / 256, 256, 0, stream>>>(deg, dinv);

    // --- transformer branch first (frees qkv/atto region for GNN) ---
    // qkv = x @ in_proj_w^T + in_proj_b
    gemm_k<true, true, false, false><<<dim3(N_NODES / 64, (3 * IN_DIM) / 64), 256, 0, stream>>>(
        x, in_proj_w, in_proj_b, nullptr, qkv, N_NODES, 3 * IN_DIM, IN_DIM);
    // attention
    attn_k<<<dim3(N_NODES / 64, HEADS), 256, 0, stream>>>(qkv, atto);
    // x_tf = atto @ out_proj_w^T + out_proj_b
    gemm_k<true, true, false, false><<<dim3(N_NODES / 64, IN_DIM / 64), 256, 0, stream>>>(
        atto, out_proj_w, out_proj_b, nullptr, xtf, N_NODES, IN_DIM, IN_DIM);
    // d_out = x_tf @ proj_w + proj_b   (x_proj intermediate, no relu yet)
    gemm_k<false, true, false, false><<<dim3(N_NODES / 64, CLASSES / 64), 256, 0, stream>>>(
        xtf, proj_w, proj_b, nullptr, out, N_NODES, CLASSES, IN_DIM);

    const int agg_blocks  = (N_NODES * (HIDDEN / 4)) / 256;   // 2048
    const int edge_blocks = (NEDGE * (HIDDEN / 4)) / 256;     // 65536
    const int br_blocks   = (N_NODES * (HIDDEN / 4)) / 256;

    // --- GCN conv 1: x @ gcn1_w -> aggregate -> +b, relu ---
    gemm_k<false, false, false, false><<<dim3(N_NODES / 64, HIDDEN / 64), 256, 0, stream>>>(
        x, gcn1_w, nullptr, nullptr, bufA, N_NODES, HIDDEN, IN_DIM);
    agg_init_k<<<agg_blocks, 256, 0, stream>>>(bufA, dinv, bufB);
    agg_edges_k<<<edge_blocks, 256, 0, stream>>>(bufA, esrc, edst, dinv, bufB);
    bias_relu_k<<<br_blocks, 256, 0, stream>>>(bufB, gcn1_b, N_NODES * (HIDDEN / 4), HIDDEN / 4);

    // --- GCN conv 2 ---
    gemm_k<false, false, false, false><<<dim3(N_NODES / 64, HIDDEN / 64), 256, 0, stream>>>(
        bufB, gcn2_w, nullptr, nullptr, bufA, N_NODES, HIDDEN, HIDDEN);
    agg_init_k<<<agg_blocks, 256, 0, stream>>>(bufA, dinv, bufB);
    agg_edges_k<<<edge_blocks, 256, 0, stream>>>(bufA, esrc, edst, dinv, bufB);
    bias_relu_k<<<br_blocks, 256, 0, stream>>>(bufB, gcn2_b, N_NODES * (HIDDEN / 4), HIDDEN / 4);

    // --- final: out = relu(bufB @ lin_w + lin_b + d_out) ---
    gemm_k<false, true, true, true><<<dim3(N_NODES / 64, CLASSES / 64), 256, 0, stream>>>(
        bufB, lin_w, lin_b, out, out, N_NODES, CLASSES, HIDDEN);
}

// Round 4
// 977.440 us; speedup vs baseline: 2.7559x; 2.7559x over previous
//
#include <hip/hip_runtime.h>
#include <hip/hip_bf16.h>

#define N_NODES 4096
#define IN_DIM  256
#define HIDDEN  512
#define CLASSES 256
#define HEADS   4
#define HD      64
#define NEDGE   131072
#define NMASK   (N_NODES - 1)

// ---------------------------------------------------------------------------
// CSR build: histogram -> prefix scan -> scatter (rebuilt every launch; cheap)
// ---------------------------------------------------------------------------
__global__ void zero_i_k(int* __restrict__ p, int n) {
    int i = blockIdx.x * 256 + threadIdx.x;
    if (i < n) p[i] = 0;
}

__global__ void hist_k(const int* __restrict__ dst, int* __restrict__ cnt) {
    int i = blockIdx.x * 256 + threadIdx.x;
    if (i < NEDGE) atomicAdd(&cnt[dst[i] & NMASK], 1);
}

// single block, 256 threads: exclusive scan of cnt[4096] -> rowptr[4097]; dinv
__global__ __launch_bounds__(256) void scan_k(const int* __restrict__ cnt,
                                              int* __restrict__ rowptr,
                                              float* __restrict__ dinv) {
    __shared__ int part[256];
    const int t = threadIdx.x;
    const int base = t * 16;
    int local[16];
    int s = 0;
    #pragma unroll
    for (int u = 0; u < 16; ++u) { local[u] = cnt[base + u]; s += local[u]; }
    part[t] = s;
    __syncthreads();
    if (t == 0) {
        int acc = 0;
        for (int i = 0; i < 256; ++i) { int v = part[i]; part[i] = acc; acc += v; }
    }
    __syncthreads();
    int acc = part[t];
    #pragma unroll
    for (int u = 0; u < 16; ++u) {
        rowptr[base + u] = acc;
        acc += local[u];
        dinv[base + u] = rsqrtf((float)local[u] + 1.0f);   // deg + self-loop
    }
    if (t == 255) rowptr[N_NODES] = acc;                   // == NEDGE
}

__global__ void scatter_k(const int* __restrict__ src, const int* __restrict__ dst,
                          const int* __restrict__ rowptr, int* __restrict__ tail,
                          int* __restrict__ ssrc) {
    int e = blockIdx.x * 256 + threadIdx.x;
    if (e >= NEDGE) return;
    int d = dst[e] & NMASK;
    int pos = rowptr[d] + atomicAdd(&tail[d], 1);
    ssrc[pos] = src[e] & NMASK;
}

// ---------------------------------------------------------------------------
// Fused GCN aggregation: out[d] = relu( dinv[d]*sum_{s in N(d)} dinv[s]*h[s]
//                                       + dinv[d]^2*h[d] + bias )
// One block (128 threads) per dst node; thread owns one float4 column of 512.
// Neighbor ids + weights staged through LDS in chunks of 64.
// ---------------------------------------------------------------------------
__global__ __launch_bounds__(128) void csr_agg_k(const float* __restrict__ h,
                                                 const int* __restrict__ rowptr,
                                                 const int* __restrict__ ssrc,
                                                 const float* __restrict__ dinv,
                                                 const float* __restrict__ bias,
                                                 float* __restrict__ out) {
    __shared__ int   nbr[64];
    __shared__ float wnb[64];
    const int d = blockIdx.x;
    const int c = threadIdx.x;            // float4 column 0..127
    const int beg = rowptr[d], end = rowptr[d + 1];

    float4 acc = {0.f, 0.f, 0.f, 0.f};
    for (int j0 = beg; j0 < end; j0 += 64) {
        const int mcnt = min(64, end - j0);
        if (c < mcnt) {
            int s = ssrc[j0 + c];
            nbr[c] = s;
            wnb[c] = dinv[s];
        }
        __syncthreads();
        for (int u = 0; u < mcnt; ++u) {
            const int s = nbr[u];
            const float w = wnb[u];
            float4 v = *((const float4*)h + (size_t)s * 128 + c);
            acc.x += w * v.x; acc.y += w * v.y;
            acc.z += w * v.z; acc.w += w * v.w;
        }
        __syncthreads();
    }

    const float wd = dinv[d];
    const float wd2 = wd * wd;
    float4 hv = *((const float4*)h + (size_t)d * 128 + c);
    float4 bv = *((const float4*)bias + c);
    float4 r;
    r.x = fmaxf(acc.x * wd + wd2 * hv.x + bv.x, 0.f);
    r.y = fmaxf(acc.y * wd + wd2 * hv.y + bv.y, 0.f);
    r.z = fmaxf(acc.z * wd + wd2 * hv.z + bv.z, 0.f);
    r.w = fmaxf(acc.w * wd + wd2 * hv.w + bv.w, 0.f);
    *((float4*)out + (size_t)d * 128 + c) = r;
}

// ---------------------------------------------------------------------------
// fp32 tiled GEMM: C[M,N] = A[M,K] @ (TRANSB ? B[N,K]^T : B[K,N])
//   optional +bias[col], +srcadd[M,N], relu.  M,N % 64 == 0, K % 16 == 0.
// 256 threads, 64x64 tile, 4x4 micro-tile per thread.
// ---------------------------------------------------------------------------
template<bool TRANSB, bool ADDBIAS, bool ADDSRC, bool RELU>
__global__ __launch_bounds__(256) void gemm_k(
    const float* __restrict__ A, const float* __restrict__ B,
    const float* __restrict__ bias, const float* srcadd,
    float* __restrict__ C, int M, int N, int K)
{
    __shared__ float As[16][68];
    __shared__ float Bs[16][68];
    const int tid = threadIdx.x;
    const int tx = tid & 15, ty = tid >> 4;
    const int m0 = blockIdx.x * 64, n0 = blockIdx.y * 64;
    const int lr  = tid >> 2;          // 0..63
    const int lc4 = (tid & 3) * 4;     // 0,4,8,12

    float acc[4][4] = {};

    for (int k0 = 0; k0 < K; k0 += 16) {
        float4 av = *(const float4*)(A + (size_t)(m0 + lr) * K + k0 + lc4);
        float4 bv;
        int bkk = 0, bc = 0;
        if (TRANSB) {
            bv = *(const float4*)(B + (size_t)(n0 + lr) * K + k0 + lc4);
        } else {
            bkk = tid >> 4;             // 0..15
            bc  = (tid & 15) * 4;       // 0..60
            bv = *(const float4*)(B + (size_t)(k0 + bkk) * N + n0 + bc);
        }
        __syncthreads();
        As[lc4 + 0][lr] = av.x; As[lc4 + 1][lr] = av.y;
        As[lc4 + 2][lr] = av.z; As[lc4 + 3][lr] = av.w;
        if (TRANSB) {
            Bs[lc4 + 0][lr] = bv.x; Bs[lc4 + 1][lr] = bv.y;
            Bs[lc4 + 2][lr] = bv.z; Bs[lc4 + 3][lr] = bv.w;
        } else {
            *(float4*)&Bs[bkk][bc] = bv;
        }
        __syncthreads();
        #pragma unroll
        for (int kk = 0; kk < 16; ++kk) {
            float4 a = *(const float4*)&As[kk][ty * 4];
            float4 b = *(const float4*)&Bs[kk][tx * 4];
            float ar[4] = {a.x, a.y, a.z, a.w};
            float br[4] = {b.x, b.y, b.z, b.w};
            #pragma unroll
            for (int i = 0; i < 4; ++i)
                #pragma unroll
                for (int j = 0; j < 4; ++j)
                    acc[i][j] += ar[i] * br[j];
        }
    }

    #pragma unroll
    for (int i = 0; i < 4; ++i) {
        int r = m0 + ty * 4 + i;
        int c = n0 + tx * 4;
        float4 v = { acc[i][0], acc[i][1], acc[i][2], acc[i][3] };
        if (ADDBIAS) {
            v.x += bias[c + 0]; v.y += bias[c + 1];
            v.z += bias[c + 2]; v.w += bias[c + 3];
        }
        if (ADDSRC) {
            float4 sv = *(const float4*)(srcadd + (size_t)r * N + c);
            v.x += sv.x; v.y += sv.y; v.z += sv.z; v.w += sv.w;
        }
        if (RELU) {
            v.x = fmaxf(v.x, 0.f); v.y = fmaxf(v.y, 0.f);
            v.z = fmaxf(v.z, 0.f); v.w = fmaxf(v.w, 0.f);
        }
        *(float4*)(C + (size_t)r * N + c) = v;
    }
}

// ---------------------------------------------------------------------------
// Flash-style fp32 attention: 4 heads, N=4096, HD=64.
// qkv: [N, 768] (q | k | v).   out: [N, 256] (heads concatenated).
// Block = 256 threads, 64 q-rows per block, k/v tiles of 64.
// ---------------------------------------------------------------------------
__global__ __launch_bounds__(256) void attn_k(const float* __restrict__ qkv,
                                              float* __restrict__ out)
{
    __shared__ float Qs[64][68];    // Qs[d][r] (scaled)
    __shared__ float KVs[64][68];   // K phase: [d][c]; V phase: [kv][d]
    __shared__ float Ps[64][68];    // Ps[kv][r]

    const int h  = blockIdx.y;
    const int q0 = blockIdx.x * 64;
    const int tid = threadIdx.x;
    const int tx = tid & 15, ty = tid >> 4;
    const int lr  = tid >> 2;         // 0..63
    const int ld4 = (tid & 3) * 4;    // 0,4,8,12
    const float scale = 0.125f;       // 1/sqrt(64)

    {   // load Q tile transposed + scaled
        const float* qp = qkv + (size_t)(q0 + lr) * 768 + h * 64 + ld4;
        #pragma unroll
        for (int u = 0; u < 4; ++u) {
            float4 v = *(const float4*)(qp + u * 16);
            int d = ld4 + u * 16;
            Qs[d + 0][lr] = v.x * scale; Qs[d + 1][lr] = v.y * scale;
            Qs[d + 2][lr] = v.z * scale; Qs[d + 3][lr] = v.w * scale;
        }
    }

    float m[4], l[4], o[4][4];
    #pragma unroll
    for (int i = 0; i < 4; ++i) {
        m[i] = -1e30f; l[i] = 0.f;
        #pragma unroll
        for (int j = 0; j < 4; ++j) o[i][j] = 0.f;
    }

    for (int kt = 0; kt < 64; ++kt) {
        const int kv0 = kt * 64;
        // K tile -> registers
        const float* kp = qkv + (size_t)(kv0 + lr) * 768 + 256 + h * 64 + ld4;
        float4 kreg[4];
        #pragma unroll
        for (int u = 0; u < 4; ++u) kreg[u] = *(const float4*)(kp + u * 16);

        __syncthreads();   // previous PV done reading KVs/Ps (also covers Qs on kt==0)
        #pragma unroll
        for (int u = 0; u < 4; ++u) {
            int d = ld4 + u * 16;
            KVs[d + 0][lr] = kreg[u].x; KVs[d + 1][lr] = kreg[u].y;
            KVs[d + 2][lr] = kreg[u].z; KVs[d + 3][lr] = kreg[u].w;
        }
        __syncthreads();

        // S = (Q*scale) K^T
        float s[4][4] = {};
        #pragma unroll
        for (int d = 0; d < 64; ++d) {
            float4 a = *(const float4*)&Qs[d][ty * 4];
            float4 b = *(const float4*)&KVs[d][tx * 4];
            float ar[4] = {a.x, a.y, a.z, a.w};
            float br[4] = {b.x, b.y, b.z, b.w};
            #pragma unroll
            for (int i = 0; i < 4; ++i)
                #pragma unroll
                for (int j = 0; j < 4; ++j)
                    s[i][j] += ar[i] * br[j];
        }

        // V tile -> registers (before overwriting KVs)
        const float* vp = qkv + (size_t)(kv0 + lr) * 768 + 512 + h * 64 + ld4;
        float4 vreg[4];
        #pragma unroll
        for (int u = 0; u < 4; ++u) vreg[u] = *(const float4*)(vp + u * 16);

        __syncthreads();   // everyone done reading K from KVs
        #pragma unroll
        for (int u = 0; u < 4; ++u)
            *(float4*)&KVs[lr][ld4 + u * 16] = vreg[u];

        // online softmax (rows r = 4*ty+i; 16 lanes per row group share ty)
        #pragma unroll
        for (int i = 0; i < 4; ++i) {
            float mx = fmaxf(fmaxf(s[i][0], s[i][1]), fmaxf(s[i][2], s[i][3]));
            mx = fmaxf(mx, __shfl_xor(mx, 1));
            mx = fmaxf(mx, __shfl_xor(mx, 2));
            mx = fmaxf(mx, __shfl_xor(mx, 4));
            mx = fmaxf(mx, __shfl_xor(mx, 8));
            float mnew = fmaxf(m[i], mx);
            float alpha = __expf(m[i] - mnew);
            float p0 = __expf(s[i][0] - mnew);
            float p1 = __expf(s[i][1] - mnew);
            float p2 = __expf(s[i][2] - mnew);
            float p3 = __expf(s[i][3] - mnew);
            float sum = p0 + p1 + p2 + p3;
            sum += __shfl_xor(sum, 1);
            sum += __shfl_xor(sum, 2);
            sum += __shfl_xor(sum, 4);
            sum += __shfl_xor(sum, 8);
            l[i] = l[i] * alpha + sum;
            m[i] = mnew;
            #pragma unroll
            for (int j = 0; j < 4; ++j) o[i][j] *= alpha;
            Ps[tx * 4 + 0][ty * 4 + i] = p0;
            Ps[tx * 4 + 1][ty * 4 + i] = p1;
            Ps[tx * 4 + 2][ty * 4 + i] = p2;
            Ps[tx * 4 + 3][ty * 4 + i] = p3;
        }
        __syncthreads();   // Ps + V ready

        // O += P V
        #pragma unroll
        for (int kv = 0; kv < 64; ++kv) {
            float4 a = *(const float4*)&Ps[kv][ty * 4];
            float4 b = *(const float4*)&KVs[kv][tx * 4];
            float ar[4] = {a.x, a.y, a.z, a.w};
            float br[4] = {b.x, b.y, b.z, b.w};
            #pragma unroll
            for (int i = 0; i < 4; ++i)
                #pragma unroll
                for (int j = 0; j < 4; ++j)
                    o[i][j] += ar[i] * br[j];
        }
    }

    #pragma unroll
    for (int i = 0; i < 4; ++i) {
        float inv = 1.0f / l[i];
        float4 v = { o[i][0] * inv, o[i][1] * inv, o[i][2] * inv, o[i][3] * inv };
        *(float4*)(out + (size_t)(q0 + ty * 4 + i) * 256 + h * 64 + tx * 4) = v;
    }
}

// ---------------------------------------------------------------------------
// Workspace (floats): dinv 4096 + reg0 4M + xtf 1M + ints(cnt/tail/rowptr/ssrc)
//   ~ 21.5 MB total.  reg0 time-shared: [qkv|atto] then [bufA|bufB].
// d_out doubles as the x_proj intermediate.
// ---------------------------------------------------------------------------
extern "C" void kernel_launch(void* const* d_in, const int* in_sizes, int n_in,
                              void* d_out, int out_size, void* d_ws, size_t ws_size,
                              hipStream_t stream)
{
    const float* x          = (const float*)d_in[0];
    const int*   eidx       = (const int*)d_in[1];
    const float* gcn1_w     = (const float*)d_in[2];
    const float* gcn1_b     = (const float*)d_in[3];
    const float* gcn2_w     = (const float*)d_in[4];
    const float* gcn2_b     = (const float*)d_in[5];
    const float* lin_w      = (const float*)d_in[6];
    const float* lin_b      = (const float*)d_in[7];
    const float* in_proj_w  = (const float*)d_in[8];
    const float* in_proj_b  = (const float*)d_in[9];
    const float* out_proj_w = (const float*)d_in[10];
    const float* out_proj_b = (const float*)d_in[11];
    const float* proj_w     = (const float*)d_in[12];
    const float* proj_b     = (const float*)d_in[13];
    float* out = (float*)d_out;

    const int* esrc = eidx;
    const int* edst = eidx + NEDGE;

    float* ws   = (float*)d_ws;
    float* dinv = ws;                              // 4096
    float* reg0 = dinv + N_NODES;                  // 4M floats, time-shared
    float* qkv  = reg0;                            // [4096 x 768]
    float* atto = reg0 + N_NODES * 3 * IN_DIM;     // [4096 x 256]
    float* bufA = reg0;                            // [4096 x 512]
    float* bufB = reg0 + N_NODES * HIDDEN;         // [4096 x 512]
    float* xtf  = reg0 + 4 * 1024 * 1024;          // [4096 x 256]
    int*   cnt    = (int*)(xtf + N_NODES * IN_DIM);
    int*   tail   = cnt + N_NODES;
    int*   rowptr = tail + N_NODES;                // 4097
    int*   ssrc   = rowptr + (N_NODES + 1);        // 131072

    // --- CSR build + dinv ---
    zero_i_k<<<(2 * N_NODES + 255) / 256, 256, 0, stream>>>(cnt, 2 * N_NODES); // cnt+tail
    hist_k<<<(NEDGE + 255) / 256, 256, 0, stream>>>(edst, cnt);
    scan_k<<<1, 256, 0, stream>>>(cnt, rowptr, dinv);
    scatter_k<<<(NEDGE + 255) / 256, 256, 0, stream>>>(esrc, edst, rowptr, tail, ssrc);

    // --- transformer branch first (frees qkv/atto region for GNN) ---
    gemm_k<true, true, false, false><<<dim3(N_NODES / 64, (3 * IN_DIM) / 64), 256, 0, stream>>>(
        x, in_proj_w, in_proj_b, nullptr, qkv, N_NODES, 3 * IN_DIM, IN_DIM);
    attn_k<<<dim3(N_NODES / 64, HEADS), 256, 0, stream>>>(qkv, atto);
    gemm_k<true, true, false, false><<<dim3(N_NODES / 64, IN_DIM / 64), 256, 0, stream>>>(
        atto, out_proj_w, out_proj_b, nullptr, xtf, N_NODES, IN_DIM, IN_DIM);
    // d_out = x_tf @ proj_w + proj_b   (x_proj intermediate, no relu yet)
    gemm_k<false, true, false, false><<<dim3(N_NODES / 64, CLASSES / 64), 256, 0, stream>>>(
        xtf, proj_w, proj_b, nullptr, out, N_NODES, CLASSES, IN_DIM);

    // --- GCN conv 1: x @ gcn1_w -> fused aggregate+bias+relu ---
    gemm_k<false, false, false, false><<<dim3(N_NODES / 64, HIDDEN / 64), 256, 0, stream>>>(
        x, gcn1_w, nullptr, nullptr, bufA, N_NODES, HIDDEN, IN_DIM);
    csr_agg_k<<<N_NODES, 128, 0, stream>>>(bufA, rowptr, ssrc, dinv, gcn1_b, bufB);

    // --- GCN conv 2 ---
    gemm_k<false, false, false, false><<<dim3(N_NODES / 64, HIDDEN / 64), 256, 0, stream>>>(
        bufB, gcn2_w, nullptr, nullptr, bufA, N_NODES, HIDDEN, HIDDEN);
    csr_agg_k<<<N_NODES, 128, 0, stream>>>(bufA, rowptr, ssrc, dinv, gcn2_b, bufB);

    // --- final: out = relu(bufB @ lin_w + lin_b + d_out) ---
    gemm_k<false, true, true, true><<<dim3(N_NODES / 64, CLASSES / 64), 256, 0, stream>>>(
        bufB, lin_w, lin_b, out, out, N_NODES, CLASSES, HIDDEN);
}

// Round 5
// 435.529 us; speedup vs baseline: 6.1850x; 2.2443x over previous
//
#include <hip/hip_runtime.h>
#include <hip/hip_bf16.h>

#define N_NODES 4096
#define IN_DIM  256
#define HIDDEN  512
#define CLASSES 256
#define HEADS   4
#define HD      64
#define NEDGE   131072
#define NMASK   (N_NODES - 1)

typedef __attribute__((ext_vector_type(8))) short bf16x8_t;
typedef __attribute__((ext_vector_type(4))) float f32x4_t;

__device__ inline ushort f2bf(float f) {
    union { float f; uint u; } v; v.f = f;
    uint r = v.u + 0x7FFF + ((v.u >> 16) & 1);   // RNE
    return (ushort)(r >> 16);
}

// ---------------------------------------------------------------------------
// CSR build: histogram -> prefix scan -> scatter (rebuilt every launch; cheap)
// ---------------------------------------------------------------------------
__global__ void zero_i_k(int* __restrict__ p, int n) {
    int i = blockIdx.x * 256 + threadIdx.x;
    if (i < n) p[i] = 0;
}

__global__ void hist_k(const int* __restrict__ dst, int* __restrict__ cnt) {
    int i = blockIdx.x * 256 + threadIdx.x;
    if (i < NEDGE) atomicAdd(&cnt[dst[i] & NMASK], 1);
}

// single block, 256 threads: exclusive scan of cnt[4096] -> rowptr[4097]; dinv
__global__ __launch_bounds__(256) void scan_k(const int* __restrict__ cnt,
                                              int* __restrict__ rowptr,
                                              float* __restrict__ dinv) {
    __shared__ int part[256];
    const int t = threadIdx.x;
    const int base = t * 16;
    int local[16];
    int s = 0;
    #pragma unroll
    for (int u = 0; u < 16; ++u) { local[u] = cnt[base + u]; s += local[u]; }
    part[t] = s;
    __syncthreads();
    if (t == 0) {
        int acc = 0;
        for (int i = 0; i < 256; ++i) { int v = part[i]; part[i] = acc; acc += v; }
    }
    __syncthreads();
    int acc = part[t];
    #pragma unroll
    for (int u = 0; u < 16; ++u) {
        rowptr[base + u] = acc;
        acc += local[u];
        dinv[base + u] = rsqrtf((float)local[u] + 1.0f);   // deg + self-loop
    }
    if (t == 255) rowptr[N_NODES] = acc;                   // == NEDGE
}

__global__ void scatter_k(const int* __restrict__ src, const int* __restrict__ dst,
                          const int* __restrict__ rowptr, int* __restrict__ tail,
                          int* __restrict__ ssrc) {
    int e = blockIdx.x * 256 + threadIdx.x;
    if (e >= NEDGE) return;
    int d = dst[e] & NMASK;
    int pos = rowptr[d] + atomicAdd(&tail[d], 1);
    ssrc[pos] = src[e] & NMASK;
}

// ---------------------------------------------------------------------------
// Fused GCN aggregation: out[d] = relu( dinv[d]*sum_{s in N(d)} dinv[s]*h[s]
//                                       + dinv[d]^2*h[d] + bias )
// ---------------------------------------------------------------------------
__global__ __launch_bounds__(128) void csr_agg_k(const float* __restrict__ h,
                                                 const int* __restrict__ rowptr,
                                                 const int* __restrict__ ssrc,
                                                 const float* __restrict__ dinv,
                                                 const float* __restrict__ bias,
                                                 float* __restrict__ out) {
    __shared__ int   nbr[64];
    __shared__ float wnb[64];
    const int d = blockIdx.x;
    const int c = threadIdx.x;            // float4 column 0..127
    const int beg = rowptr[d], end = rowptr[d + 1];

    float4 acc = {0.f, 0.f, 0.f, 0.f};
    for (int j0 = beg; j0 < end; j0 += 64) {
        const int mcnt = min(64, end - j0);
        if (c < mcnt) {
            int s = ssrc[j0 + c];
            nbr[c] = s;
            wnb[c] = dinv[s];
        }
        __syncthreads();
        for (int u = 0; u < mcnt; ++u) {
            const int s = nbr[u];
            const float w = wnb[u];
            float4 v = *((const float4*)h + (size_t)s * 128 + c);
            acc.x += w * v.x; acc.y += w * v.y;
            acc.z += w * v.z; acc.w += w * v.w;
        }
        __syncthreads();
    }

    const float wd = dinv[d];
    const float wd2 = wd * wd;
    float4 hv = *((const float4*)h + (size_t)d * 128 + c);
    float4 bv = *((const float4*)bias + c);
    float4 r;
    r.x = fmaxf(acc.x * wd + wd2 * hv.x + bv.x, 0.f);
    r.y = fmaxf(acc.y * wd + wd2 * hv.y + bv.y, 0.f);
    r.z = fmaxf(acc.z * wd + wd2 * hv.z + bv.z, 0.f);
    r.w = fmaxf(acc.w * wd + wd2 * hv.w + bv.w, 0.f);
    *((float4*)out + (size_t)d * 128 + c) = r;
}

// ---------------------------------------------------------------------------
// fp32 tiled GEMM: C[M,N] = A[M,K] @ (TRANSB ? B[N,K]^T : B[K,N])
// ---------------------------------------------------------------------------
template<bool TRANSB, bool ADDBIAS, bool ADDSRC, bool RELU>
__global__ __launch_bounds__(256) void gemm_k(
    const float* __restrict__ A, const float* __restrict__ B,
    const float* __restrict__ bias, const float* srcadd,
    float* __restrict__ C, int M, int N, int K)
{
    __shared__ float As[16][68];
    __shared__ float Bs[16][68];
    const int tid = threadIdx.x;
    const int tx = tid & 15, ty = tid >> 4;
    const int m0 = blockIdx.x * 64, n0 = blockIdx.y * 64;
    const int lr  = tid >> 2;          // 0..63
    const int lc4 = (tid & 3) * 4;     // 0,4,8,12

    float acc[4][4] = {};

    for (int k0 = 0; k0 < K; k0 += 16) {
        float4 av = *(const float4*)(A + (size_t)(m0 + lr) * K + k0 + lc4);
        float4 bv;
        int bkk = 0, bc = 0;
        if (TRANSB) {
            bv = *(const float4*)(B + (size_t)(n0 + lr) * K + k0 + lc4);
        } else {
            bkk = tid >> 4;
            bc  = (tid & 15) * 4;
            bv = *(const float4*)(B + (size_t)(k0 + bkk) * N + n0 + bc);
        }
        __syncthreads();
        As[lc4 + 0][lr] = av.x; As[lc4 + 1][lr] = av.y;
        As[lc4 + 2][lr] = av.z; As[lc4 + 3][lr] = av.w;
        if (TRANSB) {
            Bs[lc4 + 0][lr] = bv.x; Bs[lc4 + 1][lr] = bv.y;
            Bs[lc4 + 2][lr] = bv.z; Bs[lc4 + 3][lr] = bv.w;
        } else {
            *(float4*)&Bs[bkk][bc] = bv;
        }
        __syncthreads();
        #pragma unroll
        for (int kk = 0; kk < 16; ++kk) {
            float4 a = *(const float4*)&As[kk][ty * 4];
            float4 b = *(const float4*)&Bs[kk][tx * 4];
            float ar[4] = {a.x, a.y, a.z, a.w};
            float br[4] = {b.x, b.y, b.z, b.w};
            #pragma unroll
            for (int i = 0; i < 4; ++i)
                #pragma unroll
                for (int j = 0; j < 4; ++j)
                    acc[i][j] += ar[i] * br[j];
        }
    }

    #pragma unroll
    for (int i = 0; i < 4; ++i) {
        int r = m0 + ty * 4 + i;
        int c = n0 + tx * 4;
        float4 v = { acc[i][0], acc[i][1], acc[i][2], acc[i][3] };
        if (ADDBIAS) {
            v.x += bias[c + 0]; v.y += bias[c + 1];
            v.z += bias[c + 2]; v.w += bias[c + 3];
        }
        if (ADDSRC) {
            float4 sv = *(const float4*)(srcadd + (size_t)r * N + c);
            v.x += sv.x; v.y += sv.y; v.z += sv.z; v.w += sv.w;
        }
        if (RELU) {
            v.x = fmaxf(v.x, 0.f); v.y = fmaxf(v.y, 0.f);
            v.z = fmaxf(v.z, 0.f); v.w = fmaxf(v.w, 0.f);
        }
        *(float4*)(C + (size_t)r * N + c) = v;
    }
}

// ---------------------------------------------------------------------------
// bf16-MFMA flash attention: 4 heads, N=4096, HD=64.
// qkv fp32 [N,768] (q|k|v) -> out fp32 [N,256].
// Block = 256 threads (4 waves), 64 q-rows/block (16 per wave), KV tiles of 64.
// mfma_f32_16x16x32_bf16: A row=lane&15,k=(lane>>4)*8+j; B k=(lane>>4)*8+j,
// col=lane&15; C col=lane&15,row=(lane>>4)*4+r  (m89-verified layouts).
// LDS rows padded to 72 bf16 (144B) -> b128 fragment reads are 2-way (free).
// ---------------------------------------------------------------------------
__global__ __launch_bounds__(256) void attn_mfma_k(const float* __restrict__ qkv,
                                                   float* __restrict__ out)
{
    __shared__ ushort Ks[64][72];       // [kv][d]
    __shared__ ushort Vs[64][72];       // [d][kv]  (transposed)
    __shared__ ushort Ps[4][16][72];    // per-wave [row][kv]

    const int h    = blockIdx.y;
    const int q0   = blockIdx.x * 64;
    const int tid  = threadIdx.x;
    const int w    = tid >> 6;          // wave 0..3
    const int lane = tid & 63;
    const int g    = lane >> 4;         // 0..3
    const int c    = lane & 15;

    // --- Q A-fragments in registers (scaled by 1/sqrt(64)) ---
    bf16x8_t qf[2];
    {
        const float* qp = qkv + (size_t)(q0 + w * 16 + c) * 768 + h * 64 + g * 8;
        #pragma unroll
        for (int ks = 0; ks < 2; ++ks) {
            float4 v0 = *(const float4*)(qp + ks * 32);
            float4 v1 = *(const float4*)(qp + ks * 32 + 4);
            bf16x8_t t;
            t[0] = (short)f2bf(v0.x * 0.125f); t[1] = (short)f2bf(v0.y * 0.125f);
            t[2] = (short)f2bf(v0.z * 0.125f); t[3] = (short)f2bf(v0.w * 0.125f);
            t[4] = (short)f2bf(v1.x * 0.125f); t[5] = (short)f2bf(v1.y * 0.125f);
            t[6] = (short)f2bf(v1.z * 0.125f); t[7] = (short)f2bf(v1.w * 0.125f);
            qf[ks] = t;
        }
    }

    f32x4_t o[4];
    float m[4], l[4];
    #pragma unroll
    for (int r = 0; r < 4; ++r) {
        m[r] = -1e30f; l[r] = 0.f;
        o[r][0] = 0.f; o[r][1] = 0.f; o[r][2] = 0.f; o[r][3] = 0.f;
    }

    // staging addresses (constant across tiles except kv0)
    const int krow = tid >> 2, kcg = (tid & 3) * 16;       // K: row, col-group
    const int vd = tid & 63, vkg = tid >> 6;               // V: d, kv-group

    for (int kt = 0; kt < 64; ++kt) {
        const int kv0 = kt * 64;
        __syncthreads();   // all waves done reading Ks/Vs of previous tile

        {   // stage K tile: [kv][d] bf16   (coalesced 64B/thread reads)
            const float* kp = qkv + (size_t)(kv0 + krow) * 768 + 256 + h * 64 + kcg;
            float4 a = *(const float4*)(kp + 0);
            float4 b = *(const float4*)(kp + 4);
            float4 e = *(const float4*)(kp + 8);
            float4 f = *(const float4*)(kp + 12);
            ushort* dst = &Ks[krow][kcg];
            dst[0]  = f2bf(a.x); dst[1]  = f2bf(a.y); dst[2]  = f2bf(a.z); dst[3]  = f2bf(a.w);
            dst[4]  = f2bf(b.x); dst[5]  = f2bf(b.y); dst[6]  = f2bf(b.z); dst[7]  = f2bf(b.w);
            dst[8]  = f2bf(e.x); dst[9]  = f2bf(e.y); dst[10] = f2bf(e.z); dst[11] = f2bf(e.w);
            dst[12] = f2bf(f.x); dst[13] = f2bf(f.y); dst[14] = f2bf(f.z); dst[15] = f2bf(f.w);
        }
        {   // stage V tile transposed: [d][kv] bf16 (lane-coalesced 256B reads)
            const float* vp = qkv + (size_t)(kv0 + vkg * 16) * 768 + 512 + h * 64 + vd;
            ushort tmp[16];
            #pragma unroll
            for (int u = 0; u < 16; ++u) tmp[u] = f2bf(vp[(size_t)u * 768]);
            ushort* dst = &Vs[vd][vkg * 16];
            #pragma unroll
            for (int u = 0; u < 16; ++u) dst[u] = tmp[u];
        }
        __syncthreads();

        // --- S = (Q*scale) @ K^T : 4 col-tiles of 16 kv ---
        f32x4_t s[4];
        #pragma unroll
        for (int t = 0; t < 4; ++t) {
            bf16x8_t b0 = *(const bf16x8_t*)&Ks[c + 16 * t][g * 8];
            bf16x8_t b1 = *(const bf16x8_t*)&Ks[c + 16 * t][g * 8 + 32];
            f32x4_t acc; acc[0] = 0.f; acc[1] = 0.f; acc[2] = 0.f; acc[3] = 0.f;
            acc = __builtin_amdgcn_mfma_f32_16x16x32_bf16(qf[0], b0, acc, 0, 0, 0);
            acc = __builtin_amdgcn_mfma_f32_16x16x32_bf16(qf[1], b1, acc, 0, 0, 0);
            s[t] = acc;
        }

        // --- online softmax (lane owns rows g*4+r, col c+16t) ---
        #pragma unroll
        for (int r = 0; r < 4; ++r) {
            float mx = fmaxf(fmaxf(s[0][r], s[1][r]), fmaxf(s[2][r], s[3][r]));
            mx = fmaxf(mx, __shfl_xor(mx, 1));
            mx = fmaxf(mx, __shfl_xor(mx, 2));
            mx = fmaxf(mx, __shfl_xor(mx, 4));
            mx = fmaxf(mx, __shfl_xor(mx, 8));
            float mn = fmaxf(m[r], mx);
            float alpha = __expf(m[r] - mn);
            m[r] = mn;
            float p0 = __expf(s[0][r] - mn);
            float p1 = __expf(s[1][r] - mn);
            float p2 = __expf(s[2][r] - mn);
            float p3 = __expf(s[3][r] - mn);
            float sum = p0 + p1 + p2 + p3;
            sum += __shfl_xor(sum, 1);
            sum += __shfl_xor(sum, 2);
            sum += __shfl_xor(sum, 4);
            sum += __shfl_xor(sum, 8);
            l[r] = l[r] * alpha + sum;
            o[0][r] *= alpha; o[1][r] *= alpha; o[2][r] *= alpha; o[3][r] *= alpha;
            ushort* pr = &Ps[w][g * 4 + r][c];
            pr[0]  = f2bf(p0);
            pr[16] = f2bf(p1);
            pr[32] = f2bf(p2);
            pr[48] = f2bf(p3);
        }
        // (same-wave LDS RAW on Ps -> compiler-inserted lgkmcnt; no barrier needed)

        // --- O += P @ V ---
        bf16x8_t pa0 = *(const bf16x8_t*)&Ps[w][c][g * 8];
        bf16x8_t pa1 = *(const bf16x8_t*)&Ps[w][c][g * 8 + 32];
        #pragma unroll
        for (int d0 = 0; d0 < 4; ++d0) {
            bf16x8_t v0 = *(const bf16x8_t*)&Vs[c + 16 * d0][g * 8];
            bf16x8_t v1 = *(const bf16x8_t*)&Vs[c + 16 * d0][g * 8 + 32];
            o[d0] = __builtin_amdgcn_mfma_f32_16x16x32_bf16(pa0, v0, o[d0], 0, 0, 0);
            o[d0] = __builtin_amdgcn_mfma_f32_16x16x32_bf16(pa1, v1, o[d0], 0, 0, 0);
        }
    }

    // --- epilogue: O /= l ---
    #pragma unroll
    for (int r = 0; r < 4; ++r) {
        float inv = 1.0f / l[r];
        float* op = out + (size_t)(q0 + w * 16 + g * 4 + r) * 256 + h * 64 + c;
        op[0]  = o[0][r] * inv;
        op[16] = o[1][r] * inv;
        op[32] = o[2][r] * inv;
        op[48] = o[3][r] * inv;
    }
}

// ---------------------------------------------------------------------------
extern "C" void kernel_launch(void* const* d_in, const int* in_sizes, int n_in,
                              void* d_out, int out_size, void* d_ws, size_t ws_size,
                              hipStream_t stream)
{
    const float* x          = (const float*)d_in[0];
    const int*   eidx       = (const int*)d_in[1];
    const float* gcn1_w     = (const float*)d_in[2];
    const float* gcn1_b     = (const float*)d_in[3];
    const float* gcn2_w     = (const float*)d_in[4];
    const float* gcn2_b     = (const float*)d_in[5];
    const float* lin_w      = (const float*)d_in[6];
    const float* lin_b      = (const float*)d_in[7];
    const float* in_proj_w  = (const float*)d_in[8];
    const float* in_proj_b  = (const float*)d_in[9];
    const float* out_proj_w = (const float*)d_in[10];
    const float* out_proj_b = (const float*)d_in[11];
    const float* proj_w     = (const float*)d_in[12];
    const float* proj_b     = (const float*)d_in[13];
    float* out = (float*)d_out;

    const int* esrc = eidx;
    const int* edst = eidx + NEDGE;

    float* ws   = (float*)d_ws;
    float* dinv = ws;                              // 4096
    float* reg0 = dinv + N_NODES;                  // 4M floats, time-shared
    float* qkv  = reg0;                            // [4096 x 768]
    float* atto = reg0 + N_NODES * 3 * IN_DIM;     // [4096 x 256]
    float* bufA = reg0;                            // [4096 x 512]
    float* bufB = reg0 + N_NODES * HIDDEN;         // [4096 x 512]
    float* xtf  = reg0 + 4 * 1024 * 1024;          // [4096 x 256]
    int*   cnt    = (int*)(xtf + N_NODES * IN_DIM);
    int*   tail   = cnt + N_NODES;
    int*   rowptr = tail + N_NODES;                // 4097
    int*   ssrc   = rowptr + (N_NODES + 1);        // 131072

    // --- CSR build + dinv ---
    zero_i_k<<<(2 * N_NODES + 255) / 256, 256, 0, stream>>>(cnt, 2 * N_NODES);
    hist_k<<<(NEDGE + 255) / 256, 256, 0, stream>>>(edst, cnt);
    scan_k<<<1, 256, 0, stream>>>(cnt, rowptr, dinv);
    scatter_k<<<(NEDGE + 255) / 256, 256, 0, stream>>>(esrc, edst, rowptr, tail, ssrc);

    // --- transformer branch first (frees qkv/atto region for GNN) ---
    gemm_k<true, true, false, false><<<dim3(N_NODES / 64, (3 * IN_DIM) / 64), 256, 0, stream>>>(
        x, in_proj_w, in_proj_b, nullptr, qkv, N_NODES, 3 * IN_DIM, IN_DIM);
    attn_mfma_k<<<dim3(N_NODES / 64, HEADS), 256, 0, stream>>>(qkv, atto);
    gemm_k<true, true, false, false><<<dim3(N_NODES / 64, IN_DIM / 64), 256, 0, stream>>>(
        atto, out_proj_w, out_proj_b, nullptr, xtf, N_NODES, IN_DIM, IN_DIM);
    // d_out = x_tf @ proj_w + proj_b   (x_proj intermediate, no relu yet)
    gemm_k<false, true, false, false><<<dim3(N_NODES / 64, CLASSES / 64), 256, 0, stream>>>(
        xtf, proj_w, proj_b, nullptr, out, N_NODES, CLASSES, IN_DIM);

    // --- GCN conv 1: x @ gcn1_w -> fused aggregate+bias+relu ---
    gemm_k<false, false, false, false><<<dim3(N_NODES / 64, HIDDEN / 64), 256, 0, stream>>>(
        x, gcn1_w, nullptr, nullptr, bufA, N_NODES, HIDDEN, IN_DIM);
    csr_agg_k<<<N_NODES, 128, 0, stream>>>(bufA, rowptr, ssrc, dinv, gcn1_b, bufB);

    // --- GCN conv 2 ---
    gemm_k<false, false, false, false><<<dim3(N_NODES / 64, HIDDEN / 64), 256, 0, stream>>>(
        bufB, gcn2_w, nullptr, nullptr, bufA, N_NODES, HIDDEN, HIDDEN);
    csr_agg_k<<<N_NODES, 128, 0, stream>>>(bufA, rowptr, ssrc, dinv, gcn2_b, bufB);

    // --- final: out = relu(bufB @ lin_w + lin_b + d_out) ---
    gemm_k<false, true, true, true><<<dim3(N_NODES / 64, CLASSES / 64), 256, 0, stream>>>(
        bufB, lin_w, lin_b, out, out, N_NODES, CLASSES, HIDDEN);
}

// Round 6
// 418.252 us; speedup vs baseline: 6.4405x; 1.0413x over previous
//
#include <hip/hip_runtime.h>
#include <hip/hip_bf16.h>

#define N_NODES 4096
#define IN_DIM  256
#define HIDDEN  512
#define CLASSES 256
#define HEADS   4
#define HD      64
#define NEDGE   131072
#define NMASK   (N_NODES - 1)

typedef __attribute__((ext_vector_type(8))) short bf16x8_t;
typedef __attribute__((ext_vector_type(4))) float f32x4_t;

__device__ inline ushort f2bf(float f) {
    union { float f; uint u; } v; v.f = f;
    uint r = v.u + 0x7FFF + ((v.u >> 16) & 1);   // RNE
    return (ushort)(r >> 16);
}
__device__ inline float bf2f(ushort u) {
    union { uint u; float f; } v; v.u = (uint)u << 16; return v.f;
}

// ---------------------------------------------------------------------------
// CSR build (unchanged from round 3/4)
// ---------------------------------------------------------------------------
__global__ void zero_i_k(int* __restrict__ p, int n) {
    int i = blockIdx.x * 256 + threadIdx.x;
    if (i < n) p[i] = 0;
}
__global__ void hist_k(const int* __restrict__ dst, int* __restrict__ cnt) {
    int i = blockIdx.x * 256 + threadIdx.x;
    if (i < NEDGE) atomicAdd(&cnt[dst[i] & NMASK], 1);
}
__global__ __launch_bounds__(256) void scan_k(const int* __restrict__ cnt,
                                              int* __restrict__ rowptr,
                                              float* __restrict__ dinv) {
    __shared__ int part[256];
    const int t = threadIdx.x;
    const int base = t * 16;
    int local[16];
    int s = 0;
    #pragma unroll
    for (int u = 0; u < 16; ++u) { local[u] = cnt[base + u]; s += local[u]; }
    part[t] = s;
    __syncthreads();
    if (t == 0) {
        int acc = 0;
        for (int i = 0; i < 256; ++i) { int v = part[i]; part[i] = acc; acc += v; }
    }
    __syncthreads();
    int acc = part[t];
    #pragma unroll
    for (int u = 0; u < 16; ++u) {
        rowptr[base + u] = acc;
        acc += local[u];
        dinv[base + u] = rsqrtf((float)local[u] + 1.0f);
    }
    if (t == 255) rowptr[N_NODES] = acc;
}
__global__ void scatter_k(const int* __restrict__ src, const int* __restrict__ dst,
                          const int* __restrict__ rowptr, int* __restrict__ tail,
                          int* __restrict__ ssrc) {
    int e = blockIdx.x * 256 + threadIdx.x;
    if (e >= NEDGE) return;
    int d = dst[e] & NMASK;
    int pos = rowptr[d] + atomicAdd(&tail[d], 1);
    ssrc[pos] = src[e] & NMASK;
}

// ---------------------------------------------------------------------------
// split: fp32 -> (hi, lo) bf16 pair, elementwise (exact two-term split)
// ---------------------------------------------------------------------------
__global__ void split_k(const float* __restrict__ in, ushort* __restrict__ hi,
                        ushort* __restrict__ lo, int n4) {
    int i = blockIdx.x * 256 + threadIdx.x;
    if (i >= n4) return;
    float4 v = ((const float4*)in)[i];
    ushort4 h, l;
    h.x = f2bf(v.x); l.x = f2bf(v.x - bf2f(h.x));
    h.y = f2bf(v.y); l.y = f2bf(v.y - bf2f(h.y));
    h.z = f2bf(v.z); l.z = f2bf(v.z - bf2f(h.z));
    h.w = f2bf(v.w); l.w = f2bf(v.w - bf2f(h.w));
    ((ushort4*)hi)[i] = h;
    ((ushort4*)lo)[i] = l;
}

// ---------------------------------------------------------------------------
// transpose + split: W[K][N] fp32 -> th/tl [N][K] bf16.  Grid (K/64, N/64).
// ---------------------------------------------------------------------------
__global__ __launch_bounds__(256) void tsplit_k(const float* __restrict__ W,
                                                ushort* __restrict__ th,
                                                ushort* __restrict__ tl,
                                                int K, int N) {
    __shared__ float T[64][68];          // 272B rows: 16B-aligned
    const int k0 = blockIdx.x * 64, n0 = blockIdx.y * 64;
    const int t = threadIdx.x;
    {
        const int r = t >> 2, q = (t & 3) * 16;
        const float* src = W + (size_t)(k0 + r) * N + n0 + q;
        #pragma unroll
        for (int i = 0; i < 4; ++i)
            *(float4*)&T[r][q + i * 4] = *(const float4*)(src + i * 4);
    }
    __syncthreads();
    const int n = t >> 2, kq = (t & 3) * 16;
    ushort hh[16], ll[16];
    #pragma unroll
    for (int i = 0; i < 16; ++i) {
        float v = T[kq + i][n];
        ushort h = f2bf(v);
        hh[i] = h; ll[i] = f2bf(v - bf2f(h));
    }
    ushort* ph = th + (size_t)(n0 + n) * K + k0 + kq;
    ushort* pl = tl + (size_t)(n0 + n) * K + k0 + kq;
    #pragma unroll
    for (int i = 0; i < 16; ++i) { ph[i] = hh[i]; pl[i] = ll[i]; }
}

// ---------------------------------------------------------------------------
// Split-bf16 GEMM: C[M,N] = (Ah+Al)[M,K] @ (Bh+Bl)[N,K]^T  via 3 MFMAs/tile.
// 256 thr = 4 waves; 64x64 tile; wave -> 32x32 quadrant; BK=32.
// Fragment layouts (m89-verified, reused from working round-4 attn):
//   A: row=lane&15, k=(lane>>4)*8+j ; B: col=lane&15, k=(lane>>4)*8+j ;
//   C: col=lane&15, row=(lane>>4)*4+r.
// MODE: 0=F32+bias, 1=F32+bias+src+relu, 2=SPLIT+bias, 3=SPLIT nobias, 4=QKV
// ---------------------------------------------------------------------------
template<int MODE>
__global__ __launch_bounds__(256) void gemm_sp_k(
    const ushort* __restrict__ Ah, const ushort* __restrict__ Al,
    const ushort* __restrict__ Bh, const ushort* __restrict__ Bl,
    const float* __restrict__ bias, const float* src,
    void* o1, void* o2, int M, int N, int K)
{
    __shared__ ushort AsH[64][32], AsL[64][32], BsH[64][32], BsL[64][32];
    const int tid = threadIdx.x;
    const int w = tid >> 6, lane = tid & 63, g = lane >> 4, c = lane & 15;
    const int wr = w >> 1, wc = w & 1;
    const int m0 = blockIdx.x * 64, n0 = blockIdx.y * 64;
    const int sr = tid >> 2, sq = (tid & 3) * 8;

    f32x4_t acc[2][2];
    #pragma unroll
    for (int i = 0; i < 2; ++i)
        #pragma unroll
        for (int j = 0; j < 2; ++j) { acc[i][j][0]=0.f; acc[i][j][1]=0.f; acc[i][j][2]=0.f; acc[i][j][3]=0.f; }

    for (int k0 = 0; k0 < K; k0 += 32) {
        __syncthreads();
        *(bf16x8_t*)&AsH[sr][sq] = *(const bf16x8_t*)(Ah + (size_t)(m0 + sr) * K + k0 + sq);
        *(bf16x8_t*)&AsL[sr][sq] = *(const bf16x8_t*)(Al + (size_t)(m0 + sr) * K + k0 + sq);
        *(bf16x8_t*)&BsH[sr][sq] = *(const bf16x8_t*)(Bh + (size_t)(n0 + sr) * K + k0 + sq);
        *(bf16x8_t*)&BsL[sr][sq] = *(const bf16x8_t*)(Bl + (size_t)(n0 + sr) * K + k0 + sq);
        __syncthreads();

        bf16x8_t aH[2], aL[2], bH[2], bL[2];
        #pragma unroll
        for (int mr = 0; mr < 2; ++mr) {
            aH[mr] = *(const bf16x8_t*)&AsH[wr * 32 + mr * 16 + c][g * 8];
            aL[mr] = *(const bf16x8_t*)&AsL[wr * 32 + mr * 16 + c][g * 8];
        }
        #pragma unroll
        for (int nr = 0; nr < 2; ++nr) {
            bH[nr] = *(const bf16x8_t*)&BsH[wc * 32 + nr * 16 + c][g * 8];
            bL[nr] = *(const bf16x8_t*)&BsL[wc * 32 + nr * 16 + c][g * 8];
        }
        #pragma unroll
        for (int mr = 0; mr < 2; ++mr)
            #pragma unroll
            for (int nr = 0; nr < 2; ++nr) {
                acc[mr][nr] = __builtin_amdgcn_mfma_f32_16x16x32_bf16(aH[mr], bH[nr], acc[mr][nr], 0, 0, 0);
                acc[mr][nr] = __builtin_amdgcn_mfma_f32_16x16x32_bf16(aH[mr], bL[nr], acc[mr][nr], 0, 0, 0);
                acc[mr][nr] = __builtin_amdgcn_mfma_f32_16x16x32_bf16(aL[mr], bH[nr], acc[mr][nr], 0, 0, 0);
            }
    }

    #pragma unroll
    for (int mr = 0; mr < 2; ++mr)
        #pragma unroll
        for (int nr = 0; nr < 2; ++nr) {
            const int col = n0 + wc * 32 + nr * 16 + c;
            #pragma unroll
            for (int j = 0; j < 4; ++j) {
                const int row = m0 + wr * 32 + mr * 16 + g * 4 + j;
                float v = acc[mr][nr][j];
                if (MODE != 3) v += bias[col];
                if (MODE == 0) {
                    ((float*)o1)[(size_t)row * N + col] = v;
                } else if (MODE == 1) {
                    v += src[(size_t)row * N + col];
                    ((float*)o1)[(size_t)row * N + col] = fmaxf(v, 0.f);
                } else if (MODE == 2 || MODE == 3) {
                    ushort h = f2bf(v);
                    ((ushort*)o1)[(size_t)row * N + col] = h;
                    ((ushort*)o2)[(size_t)row * N + col] = f2bf(v - bf2f(h));
                } else {  // QKV: bf16 out, q cols pre-scaled
                    if (col < 256) v *= 0.125f;
                    ((ushort*)o1)[(size_t)row * N + col] = f2bf(v);
                }
            }
        }
}

// ---------------------------------------------------------------------------
// V transpose: qkvb v-section [n][hd] -> vt[h][d][n].  Grid (4096/64, 4).
// ---------------------------------------------------------------------------
__global__ __launch_bounds__(256) void vtrans_k(const ushort* __restrict__ qkvb,
                                                ushort* __restrict__ vt) {
    __shared__ ushort T[64][72];
    const int n0 = blockIdx.x * 64;
    const int h  = blockIdx.y;
    const int t  = threadIdx.x;
    {
        const int r = t >> 2, q = (t & 3) * 16;
        const ushort* src = qkvb + (size_t)(n0 + r) * 768 + 512 + h * 64 + q;
        *(bf16x8_t*)&T[r][q]     = *(const bf16x8_t*)(src);
        *(bf16x8_t*)&T[r][q + 8] = *(const bf16x8_t*)(src + 8);
    }
    __syncthreads();
    const int d = t >> 2, nq = (t & 3) * 16;
    ushort tmp[16];
    #pragma unroll
    for (int i = 0; i < 16; ++i) tmp[i] = T[nq + i][d];
    ushort* dst = vt + (size_t)(h * 64 + d) * 4096 + n0 + nq;
    #pragma unroll
    for (int i = 0; i < 16; ++i) dst[i] = tmp[i];
}

// ---------------------------------------------------------------------------
// bf16-MFMA flash attention, staged from pre-converted bf16.
// qkvb [4096][768] bf16 (q pre-scaled), vt [4][64][4096] bf16.
// Out: atto split hi/lo [4096][256].
// 128 thr = 2 waves; 32 q-rows/block (16/wave); KV tile 64. Grid (128, 4).
// ---------------------------------------------------------------------------
__global__ __launch_bounds__(128) void attn2_k(const ushort* __restrict__ qkvb,
                                               const ushort* __restrict__ vt,
                                               ushort* __restrict__ aoh,
                                               ushort* __restrict__ aol)
{
    __shared__ ushort Ks[64][72];       // [kv][d]
    __shared__ ushort Vs[64][72];       // [d][kv]
    __shared__ ushort Ps[2][16][72];    // per-wave [q-row][kv]

    const int h    = blockIdx.y;
    const int q0   = blockIdx.x * 32;
    const int tid  = threadIdx.x;
    const int w    = tid >> 6;          // wave 0..1
    const int lane = tid & 63;
    const int g    = lane >> 4;
    const int c    = lane & 15;

    // Q A-fragments (already scaled in qkvb)
    bf16x8_t qf[2];
    {
        const ushort* qp = qkvb + (size_t)(q0 + w * 16 + c) * 768 + h * 64;
        qf[0] = *(const bf16x8_t*)(qp + g * 8);
        qf[1] = *(const bf16x8_t*)(qp + g * 8 + 32);
    }

    f32x4_t o[4];
    float m[4], l[4];
    #pragma unroll
    for (int r = 0; r < 4; ++r) {
        m[r] = -1e30f; l[r] = 0.f;
        o[r][0] = 0.f; o[r][1] = 0.f; o[r][2] = 0.f; o[r][3] = 0.f;
    }

    const int srow = tid >> 1, shalf = (tid & 1) * 32;   // staging: row, 32-col half

    for (int kt = 0; kt < 64; ++kt) {
        const int kv0 = kt * 64;
        __syncthreads();
        {   // K tile: rows of qkvb k-section (contiguous 64B per thread)
            const ushort* kp = qkvb + (size_t)(kv0 + srow) * 768 + 256 + h * 64 + shalf;
            #pragma unroll
            for (int i = 0; i < 4; ++i)
                *(bf16x8_t*)&Ks[srow][shalf + i * 8] = *(const bf16x8_t*)(kp + i * 8);
        }
        {   // V tile: rows of vt (contiguous 64B per thread)
            const ushort* vp = vt + (size_t)(h * 64 + srow) * 4096 + kv0 + shalf;
            #pragma unroll
            for (int i = 0; i < 4; ++i)
                *(bf16x8_t*)&Vs[srow][shalf + i * 8] = *(const bf16x8_t*)(vp + i * 8);
        }
        __syncthreads();

        // S = Qs @ K^T
        f32x4_t s[4];
        #pragma unroll
        for (int t = 0; t < 4; ++t) {
            bf16x8_t b0 = *(const bf16x8_t*)&Ks[c + 16 * t][g * 8];
            bf16x8_t b1 = *(const bf16x8_t*)&Ks[c + 16 * t][g * 8 + 32];
            f32x4_t a; a[0] = 0.f; a[1] = 0.f; a[2] = 0.f; a[3] = 0.f;
            a = __builtin_amdgcn_mfma_f32_16x16x32_bf16(qf[0], b0, a, 0, 0, 0);
            a = __builtin_amdgcn_mfma_f32_16x16x32_bf16(qf[1], b1, a, 0, 0, 0);
            s[t] = a;
        }

        // online softmax
        #pragma unroll
        for (int r = 0; r < 4; ++r) {
            float mx = fmaxf(fmaxf(s[0][r], s[1][r]), fmaxf(s[2][r], s[3][r]));
            mx = fmaxf(mx, __shfl_xor(mx, 1));
            mx = fmaxf(mx, __shfl_xor(mx, 2));
            mx = fmaxf(mx, __shfl_xor(mx, 4));
            mx = fmaxf(mx, __shfl_xor(mx, 8));
            float mn = fmaxf(m[r], mx);
            float alpha = __expf(m[r] - mn);
            m[r] = mn;
            float p0 = __expf(s[0][r] - mn);
            float p1 = __expf(s[1][r] - mn);
            float p2 = __expf(s[2][r] - mn);
            float p3 = __expf(s[3][r] - mn);
            float sum = p0 + p1 + p2 + p3;
            sum += __shfl_xor(sum, 1);
            sum += __shfl_xor(sum, 2);
            sum += __shfl_xor(sum, 4);
            sum += __shfl_xor(sum, 8);
            l[r] = l[r] * alpha + sum;
            o[0][r] *= alpha; o[1][r] *= alpha; o[2][r] *= alpha; o[3][r] *= alpha;
            ushort* pr = &Ps[w][g * 4 + r][c];
            pr[0]  = f2bf(p0);
            pr[16] = f2bf(p1);
            pr[32] = f2bf(p2);
            pr[48] = f2bf(p3);
        }
        // same-wave LDS RAW on Ps: compiler-inserted lgkmcnt suffices

        // O += P @ V
        bf16x8_t pa0 = *(const bf16x8_t*)&Ps[w][c][g * 8];
        bf16x8_t pa1 = *(const bf16x8_t*)&Ps[w][c][g * 8 + 32];
        #pragma unroll
        for (int d0 = 0; d0 < 4; ++d0) {
            bf16x8_t v0 = *(const bf16x8_t*)&Vs[c + 16 * d0][g * 8];
            bf16x8_t v1 = *(const bf16x8_t*)&Vs[c + 16 * d0][g * 8 + 32];
            o[d0] = __builtin_amdgcn_mfma_f32_16x16x32_bf16(pa0, v0, o[d0], 0, 0, 0);
            o[d0] = __builtin_amdgcn_mfma_f32_16x16x32_bf16(pa1, v1, o[d0], 0, 0, 0);
        }
    }

    // epilogue: split write of O/l
    #pragma unroll
    for (int r = 0; r < 4; ++r) {
        float inv = 1.0f / l[r];
        const size_t row = (size_t)(q0 + w * 16 + g * 4 + r) * 256 + h * 64 + c;
        #pragma unroll
        for (int d0 = 0; d0 < 4; ++d0) {
            float v = o[d0][r] * inv;
            ushort hi = f2bf(v);
            aoh[row + 16 * d0] = hi;
            aol[row + 16 * d0] = f2bf(v - bf2f(hi));
        }
    }
}

// ---------------------------------------------------------------------------
// Fused GCN aggregation on split operands:
// out = relu( dinv[d]*sum dinv[s]*h[s] + dinv[d]^2*h[d] + bias ), h = hi+lo.
// ---------------------------------------------------------------------------
__global__ __launch_bounds__(128) void csr_agg2_k(const ushort* __restrict__ hh,
                                                  const ushort* __restrict__ hl,
                                                  const int* __restrict__ rowptr,
                                                  const int* __restrict__ ssrc,
                                                  const float* __restrict__ dinv,
                                                  const float* __restrict__ bias,
                                                  ushort* __restrict__ oh,
                                                  ushort* __restrict__ ol) {
    __shared__ int   nbr[64];
    __shared__ float wnb[64];
    const int d = blockIdx.x;
    const int c = threadIdx.x;            // ushort4 column 0..127 of 512
    const int beg = rowptr[d], end = rowptr[d + 1];

    float4 acc = {0.f, 0.f, 0.f, 0.f};
    for (int j0 = beg; j0 < end; j0 += 64) {
        const int mcnt = min(64, end - j0);
        if (c < mcnt) {
            int s = ssrc[j0 + c];
            nbr[c] = s;
            wnb[c] = dinv[s];
        }
        __syncthreads();
        for (int u = 0; u < mcnt; ++u) {
            const int s = nbr[u];
            const float w = wnb[u];
            ushort4 vh = *(const ushort4*)(hh + (size_t)s * 512 + c * 4);
            ushort4 vl = *(const ushort4*)(hl + (size_t)s * 512 + c * 4);
            acc.x += w * (bf2f(vh.x) + bf2f(vl.x));
            acc.y += w * (bf2f(vh.y) + bf2f(vl.y));
            acc.z += w * (bf2f(vh.z) + bf2f(vl.z));
            acc.w += w * (bf2f(vh.w) + bf2f(vl.w));
        }
        __syncthreads();
    }

    const float wd = dinv[d];
    const float wd2 = wd * wd;
    ushort4 sh = *(const ushort4*)(hh + (size_t)d * 512 + c * 4);
    ushort4 sl = *(const ushort4*)(hl + (size_t)d * 512 + c * 4);
    float4 bv = *((const float4*)bias + c);
    float r0 = fmaxf(acc.x * wd + wd2 * (bf2f(sh.x) + bf2f(sl.x)) + bv.x, 0.f);
    float r1 = fmaxf(acc.y * wd + wd2 * (bf2f(sh.y) + bf2f(sl.y)) + bv.y, 0.f);
    float r2 = fmaxf(acc.z * wd + wd2 * (bf2f(sh.z) + bf2f(sl.z)) + bv.z, 0.f);
    float r3 = fmaxf(acc.w * wd + wd2 * (bf2f(sh.w) + bf2f(sl.w)) + bv.w, 0.f);
    ushort4 H, L;
    H.x = f2bf(r0); L.x = f2bf(r0 - bf2f(H.x));
    H.y = f2bf(r1); L.y = f2bf(r1 - bf2f(H.y));
    H.z = f2bf(r2); L.z = f2bf(r2 - bf2f(H.z));
    H.w = f2bf(r3); L.w = f2bf(r3 - bf2f(H.w));
    *(ushort4*)(oh + (size_t)d * 512 + c * 4) = H;
    *(ushort4*)(ol + (size_t)d * 512 + c * 4) = L;
}

// ---------------------------------------------------------------------------
// Workspace ~22.6 MB, time-shared regions (proven-safe size range).
// ---------------------------------------------------------------------------
extern "C" void kernel_launch(void* const* d_in, const int* in_sizes, int n_in,
                              void* d_out, int out_size, void* d_ws, size_t ws_size,
                              hipStream_t stream)
{
    const float* x          = (const float*)d_in[0];
    const int*   eidx       = (const int*)d_in[1];
    const float* gcn1_w     = (const float*)d_in[2];
    const float* gcn1_b     = (const float*)d_in[3];
    const float* gcn2_w     = (const float*)d_in[4];
    const float* gcn2_b     = (const float*)d_in[5];
    const float* lin_w      = (const float*)d_in[6];
    const float* lin_b      = (const float*)d_in[7];
    const float* in_proj_w  = (const float*)d_in[8];
    const float* in_proj_b  = (const float*)d_in[9];
    const float* out_proj_w = (const float*)d_in[10];
    const float* out_proj_b = (const float*)d_in[11];
    const float* proj_w     = (const float*)d_in[12];
    const float* proj_b     = (const float*)d_in[13];
    float* out = (float*)d_out;

    const int* esrc = eidx;
    const int* edst = eidx + NEDGE;

    char* base = (char*)d_ws;
    size_t off = 0;
    auto take = [&](size_t bytes) -> char* {
        char* p = base + off;
        off = (off + bytes + 255) & ~(size_t)255;
        return p;
    };

    int*   cnt    = (int*)take(N_NODES * 4);
    int*   tail   = (int*)take(N_NODES * 4);
    int*   rowptr = (int*)take((N_NODES + 8) * 4);
    int*   ssrc   = (int*)take(NEDGE * 4);
    float* dinv   = (float*)take(N_NODES * 4);

    // weight region (2 MB), time-shared transformer -> gcn
    ushort* wreg = (ushort*)take(2 * 1024 * 1024);
    ushort* ipW_h = wreg;                    // 768*256
    ushort* ipW_l = ipW_h + 768 * 256;
    ushort* opW_h = ipW_l + 768 * 256;       // 256*256
    ushort* opW_l = opW_h + 256 * 256;
    ushort* pjT_h = opW_l + 256 * 256;       // 256*256
    ushort* pjT_l = pjT_h + 256 * 256;
    ushort* g1T_h = wreg;                    // [512][256]
    ushort* g1T_l = g1T_h + 512 * 256;
    ushort* g2T_h = g1T_l + 512 * 256;       // [512][512]
    ushort* g2T_l = g2T_h + 512 * 512;
    ushort* lT_h  = g2T_l + 512 * 512;       // [256][512]
    ushort* lT_l  = lT_h + 256 * 512;

    // xs (x split), 4 MB
    ushort* xs_h = (ushort*)take(N_NODES * IN_DIM * 2);
    ushort* xs_l = (ushort*)take(N_NODES * IN_DIM * 2);

    // R2 (8 MB): qkvb + vt  |  later GCN ping (Ph, Pl)
    char* R2 = take(8 * 1024 * 1024);
    ushort* qkvb = (ushort*)R2;                          // 4096*768
    ushort* vt   = qkvb + (size_t)N_NODES * 768;         // 4*64*4096
    ushort* Ph   = (ushort*)R2;                          // 4096*512
    ushort* Pl   = Ph + (size_t)N_NODES * HIDDEN;

    // R3 (8 MB): atto + xtf splits  |  later GCN pong (Qh, Ql)
    char* R3 = take(8 * 1024 * 1024);
    ushort* ao_h = (ushort*)R3;                          // 4096*256
    ushort* ao_l = ao_h + (size_t)N_NODES * IN_DIM;
    ushort* xt_h = ao_l + (size_t)N_NODES * IN_DIM;
    ushort* xt_l = xt_h + (size_t)N_NODES * IN_DIM;
    ushort* Qh   = (ushort*)R3;                          // 4096*512
    ushort* Ql   = Qh + (size_t)N_NODES * HIDDEN;

    // --- CSR + dinv ---
    zero_i_k<<<(2 * N_NODES + 255) / 256, 256, 0, stream>>>(cnt, 2 * N_NODES);
    hist_k<<<(NEDGE + 255) / 256, 256, 0, stream>>>(edst, cnt);
    scan_k<<<1, 256, 0, stream>>>(cnt, rowptr, dinv);
    scatter_k<<<(NEDGE + 255) / 256, 256, 0, stream>>>(esrc, edst, rowptr, tail, ssrc);

    // --- input / transformer weight prep ---
    split_k<<<(N_NODES * IN_DIM / 4 + 255) / 256, 256, 0, stream>>>(x, xs_h, xs_l, N_NODES * IN_DIM / 4);
    split_k<<<(768 * 256 / 4 + 255) / 256, 256, 0, stream>>>(in_proj_w, ipW_h, ipW_l, 768 * 256 / 4);
    split_k<<<(256 * 256 / 4 + 255) / 256, 256, 0, stream>>>(out_proj_w, opW_h, opW_l, 256 * 256 / 4);
    tsplit_k<<<dim3(4, 4), 256, 0, stream>>>(proj_w, pjT_h, pjT_l, 256, 256);

    // --- transformer branch ---
    gemm_sp_k<4><<<dim3(64, 12), 256, 0, stream>>>(xs_h, xs_l, ipW_h, ipW_l,
        in_proj_b, nullptr, qkvb, nullptr, N_NODES, 768, 256);
    vtrans_k<<<dim3(64, 4), 256, 0, stream>>>(qkvb, vt);
    attn2_k<<<dim3(128, 4), 128, 0, stream>>>(qkvb, vt, ao_h, ao_l);
    gemm_sp_k<2><<<dim3(64, 4), 256, 0, stream>>>(ao_h, ao_l, opW_h, opW_l,
        out_proj_b, nullptr, xt_h, xt_l, N_NODES, 256, 256);
    gemm_sp_k<0><<<dim3(64, 4), 256, 0, stream>>>(xt_h, xt_l, pjT_h, pjT_l,
        proj_b, nullptr, out, nullptr, N_NODES, 256, 256);

    // --- gcn weight prep (overwrites transformer weights; stream-ordered) ---
    tsplit_k<<<dim3(4, 8), 256, 0, stream>>>(gcn1_w, g1T_h, g1T_l, 256, 512);
    tsplit_k<<<dim3(8, 8), 256, 0, stream>>>(gcn2_w, g2T_h, g2T_l, 512, 512);
    tsplit_k<<<dim3(8, 4), 256, 0, stream>>>(lin_w, lT_h, lT_l, 512, 256);

    // --- GCN branch ---
    gemm_sp_k<3><<<dim3(64, 8), 256, 0, stream>>>(xs_h, xs_l, g1T_h, g1T_l,
        nullptr, nullptr, Ph, Pl, N_NODES, HIDDEN, IN_DIM);
    csr_agg2_k<<<N_NODES, 128, 0, stream>>>(Ph, Pl, rowptr, ssrc, dinv, gcn1_b, Qh, Ql);
    gemm_sp_k<3><<<dim3(64, 8), 256, 0, stream>>>(Qh, Ql, g2T_h, g2T_l,
        nullptr, nullptr, Ph, Pl, N_NODES, HIDDEN, HIDDEN);
    csr_agg2_k<<<N_NODES, 128, 0, stream>>>(Ph, Pl, rowptr, ssrc, dinv, gcn2_b, Qh, Ql);

    // --- final: out = relu(h2 @ lin_w + lin_b + x_proj) ---
    gemm_sp_k<1><<<dim3(64, 4), 256, 0, stream>>>(Qh, Ql, lT_h, lT_l,
        lin_b, out, out, nullptr, N_NODES, CLASSES, HIDDEN);
}

// Round 7
// 375.686 us; speedup vs baseline: 7.1702x; 1.1133x over previous
//
#include <hip/hip_runtime.h>
#include <hip/hip_bf16.h>

#define N_NODES 4096
#define IN_DIM  256
#define HIDDEN  512
#define CLASSES 256
#define HEADS   4
#define HD      64
#define NEDGE   131072
#define NMASK   (N_NODES - 1)

typedef __attribute__((ext_vector_type(8))) short bf16x8_t;
typedef __attribute__((ext_vector_type(4))) float f32x4_t;

__device__ inline ushort f2bf(float f) {
    union { float f; uint u; } v; v.f = f;
    uint r = v.u + 0x7FFF + ((v.u >> 16) & 1);   // RNE
    return (ushort)(r >> 16);
}
__device__ inline float bf2f(ushort u) {
    union { uint u; float f; } v; v.u = (uint)u << 16; return v.f;
}

// ---------------------------------------------------------------------------
// CSR build (unchanged)
// ---------------------------------------------------------------------------
__global__ void zero_i_k(int* __restrict__ p, int n) {
    int i = blockIdx.x * 256 + threadIdx.x;
    if (i < n) p[i] = 0;
}
__global__ void hist_k(const int* __restrict__ dst, int* __restrict__ cnt) {
    int i = blockIdx.x * 256 + threadIdx.x;
    if (i < NEDGE) atomicAdd(&cnt[dst[i] & NMASK], 1);
}
__global__ __launch_bounds__(256) void scan_k(const int* __restrict__ cnt,
                                              int* __restrict__ rowptr,
                                              float* __restrict__ dinv) {
    __shared__ int part[256];
    const int t = threadIdx.x;
    const int base = t * 16;
    int local[16];
    int s = 0;
    #pragma unroll
    for (int u = 0; u < 16; ++u) { local[u] = cnt[base + u]; s += local[u]; }
    part[t] = s;
    __syncthreads();
    if (t == 0) {
        int acc = 0;
        for (int i = 0; i < 256; ++i) { int v = part[i]; part[i] = acc; acc += v; }
    }
    __syncthreads();
    int acc = part[t];
    #pragma unroll
    for (int u = 0; u < 16; ++u) {
        rowptr[base + u] = acc;
        acc += local[u];
        dinv[base + u] = rsqrtf((float)local[u] + 1.0f);
    }
    if (t == 255) rowptr[N_NODES] = acc;
}
__global__ void scatter_k(const int* __restrict__ src, const int* __restrict__ dst,
                          const int* __restrict__ rowptr, int* __restrict__ tail,
                          int* __restrict__ ssrc) {
    int e = blockIdx.x * 256 + threadIdx.x;
    if (e >= NEDGE) return;
    int d = dst[e] & NMASK;
    int pos = rowptr[d] + atomicAdd(&tail[d], 1);
    ssrc[pos] = src[e] & NMASK;
}

// ---------------------------------------------------------------------------
// split: fp32 -> (hi, lo) bf16 pair
// ---------------------------------------------------------------------------
__global__ void split_k(const float* __restrict__ in, ushort* __restrict__ hi,
                        ushort* __restrict__ lo, int n4) {
    int i = blockIdx.x * 256 + threadIdx.x;
    if (i >= n4) return;
    float4 v = ((const float4*)in)[i];
    ushort4 h, l;
    h.x = f2bf(v.x); l.x = f2bf(v.x - bf2f(h.x));
    h.y = f2bf(v.y); l.y = f2bf(v.y - bf2f(h.y));
    h.z = f2bf(v.z); l.z = f2bf(v.z - bf2f(h.z));
    h.w = f2bf(v.w); l.w = f2bf(v.w - bf2f(h.w));
    ((ushort4*)hi)[i] = h;
    ((ushort4*)lo)[i] = l;
}

// ---------------------------------------------------------------------------
// transpose + split: W[K][N] fp32 -> th/tl [N][K] bf16.  Grid (K/64, N/64).
// ---------------------------------------------------------------------------
__global__ __launch_bounds__(256) void tsplit_k(const float* __restrict__ W,
                                                ushort* __restrict__ th,
                                                ushort* __restrict__ tl,
                                                int K, int N) {
    __shared__ float T[64][68];
    const int k0 = blockIdx.x * 64, n0 = blockIdx.y * 64;
    const int t = threadIdx.x;
    {
        const int r = t >> 2, q = (t & 3) * 16;
        const float* src = W + (size_t)(k0 + r) * N + n0 + q;
        #pragma unroll
        for (int i = 0; i < 4; ++i)
            *(float4*)&T[r][q + i * 4] = *(const float4*)(src + i * 4);
    }
    __syncthreads();
    const int n = t >> 2, kq = (t & 3) * 16;
    ushort hh[16], ll[16];
    #pragma unroll
    for (int i = 0; i < 16; ++i) {
        float v = T[kq + i][n];
        ushort h = f2bf(v);
        hh[i] = h; ll[i] = f2bf(v - bf2f(h));
    }
    ushort* ph = th + (size_t)(n0 + n) * K + k0 + kq;
    ushort* pl = tl + (size_t)(n0 + n) * K + k0 + kq;
    #pragma unroll
    for (int i = 0; i < 16; ++i) { ph[i] = hh[i]; pl[i] = ll[i]; }
}

// ---------------------------------------------------------------------------
// Split-bf16 GEMM (unchanged from round 5)
// MODE: 0=F32+bias, 1=F32+bias+src+relu, 2=SPLIT+bias, 3=SPLIT nobias, 4=QKV
// ---------------------------------------------------------------------------
template<int MODE>
__global__ __launch_bounds__(256) void gemm_sp_k(
    const ushort* __restrict__ Ah, const ushort* __restrict__ Al,
    const ushort* __restrict__ Bh, const ushort* __restrict__ Bl,
    const float* __restrict__ bias, const float* src,
    void* o1, void* o2, int M, int N, int K)
{
    __shared__ ushort AsH[64][32], AsL[64][32], BsH[64][32], BsL[64][32];
    const int tid = threadIdx.x;
    const int w = tid >> 6, lane = tid & 63, g = lane >> 4, c = lane & 15;
    const int wr = w >> 1, wc = w & 1;
    const int m0 = blockIdx.x * 64, n0 = blockIdx.y * 64;
    const int sr = tid >> 2, sq = (tid & 3) * 8;

    f32x4_t acc[2][2];
    #pragma unroll
    for (int i = 0; i < 2; ++i)
        #pragma unroll
        for (int j = 0; j < 2; ++j) { acc[i][j][0]=0.f; acc[i][j][1]=0.f; acc[i][j][2]=0.f; acc[i][j][3]=0.f; }

    for (int k0 = 0; k0 < K; k0 += 32) {
        __syncthreads();
        *(bf16x8_t*)&AsH[sr][sq] = *(const bf16x8_t*)(Ah + (size_t)(m0 + sr) * K + k0 + sq);
        *(bf16x8_t*)&AsL[sr][sq] = *(const bf16x8_t*)(Al + (size_t)(m0 + sr) * K + k0 + sq);
        *(bf16x8_t*)&BsH[sr][sq] = *(const bf16x8_t*)(Bh + (size_t)(n0 + sr) * K + k0 + sq);
        *(bf16x8_t*)&BsL[sr][sq] = *(const bf16x8_t*)(Bl + (size_t)(n0 + sr) * K + k0 + sq);
        __syncthreads();

        bf16x8_t aH[2], aL[2], bH[2], bL[2];
        #pragma unroll
        for (int mr = 0; mr < 2; ++mr) {
            aH[mr] = *(const bf16x8_t*)&AsH[wr * 32 + mr * 16 + c][g * 8];
            aL[mr] = *(const bf16x8_t*)&AsL[wr * 32 + mr * 16 + c][g * 8];
        }
        #pragma unroll
        for (int nr = 0; nr < 2; ++nr) {
            bH[nr] = *(const bf16x8_t*)&BsH[wc * 32 + nr * 16 + c][g * 8];
            bL[nr] = *(const bf16x8_t*)&BsL[wc * 32 + nr * 16 + c][g * 8];
        }
        #pragma unroll
        for (int mr = 0; mr < 2; ++mr)
            #pragma unroll
            for (int nr = 0; nr < 2; ++nr) {
                acc[mr][nr] = __builtin_amdgcn_mfma_f32_16x16x32_bf16(aH[mr], bH[nr], acc[mr][nr], 0, 0, 0);
                acc[mr][nr] = __builtin_amdgcn_mfma_f32_16x16x32_bf16(aH[mr], bL[nr], acc[mr][nr], 0, 0, 0);
                acc[mr][nr] = __builtin_amdgcn_mfma_f32_16x16x32_bf16(aL[mr], bH[nr], acc[mr][nr], 0, 0, 0);
            }
    }

    #pragma unroll
    for (int mr = 0; mr < 2; ++mr)
        #pragma unroll
        for (int nr = 0; nr < 2; ++nr) {
            const int col = n0 + wc * 32 + nr * 16 + c;
            #pragma unroll
            for (int j = 0; j < 4; ++j) {
                const int row = m0 + wr * 32 + mr * 16 + g * 4 + j;
                float v = acc[mr][nr][j];
                if (MODE != 3) v += bias[col];
                if (MODE == 0) {
                    ((float*)o1)[(size_t)row * N + col] = v;
                } else if (MODE == 1) {
                    v += src[(size_t)row * N + col];
                    ((float*)o1)[(size_t)row * N + col] = fmaxf(v, 0.f);
                } else if (MODE == 2 || MODE == 3) {
                    ushort h = f2bf(v);
                    ((ushort*)o1)[(size_t)row * N + col] = h;
                    ((ushort*)o2)[(size_t)row * N + col] = f2bf(v - bf2f(h));
                } else {  // QKV: bf16 out, q cols pre-scaled
                    if (col < 256) v *= 0.125f;
                    ((ushort*)o1)[(size_t)row * N + col] = f2bf(v);
                }
            }
        }
}

// ---------------------------------------------------------------------------
// V transpose: qkvb v-section [n][hd] -> vt[h][d][n].  Grid (4096/64, 4).
// ---------------------------------------------------------------------------
__global__ __launch_bounds__(256) void vtrans_k(const ushort* __restrict__ qkvb,
                                                ushort* __restrict__ vt) {
    __shared__ ushort T[64][72];
    const int n0 = blockIdx.x * 64;
    const int h  = blockIdx.y;
    const int t  = threadIdx.x;
    {
        const int r = t >> 2, q = (t & 3) * 16;
        const ushort* src = qkvb + (size_t)(n0 + r) * 768 + 512 + h * 64 + q;
        *(bf16x8_t*)&T[r][q]     = *(const bf16x8_t*)(src);
        *(bf16x8_t*)&T[r][q + 8] = *(const bf16x8_t*)(src + 8);
    }
    __syncthreads();
    const int d = t >> 2, nq = (t & 3) * 16;
    ushort tmp[16];
    #pragma unroll
    for (int i = 0; i < 16; ++i) tmp[i] = T[nq + i][d];
    ushort* dst = vt + (size_t)(h * 64 + d) * 4096 + n0 + nq;
    #pragma unroll
    for (int i = 0; i < 16; ++i) dst[i] = tmp[i];
}

// ---------------------------------------------------------------------------
// Barrier-free split-KV flash attention.
// One 64-thread wave per (16 q-rows, head, kv-split-half).
// K/V MFMA B-fragments loaded DIRECTLY from L2-resident qkvb / vt
// (16B contiguous per lane) -- no K/V LDS, no __syncthreads.
// Outputs UNnormalized partial O (fp32) + per-row (m, l).
// ---------------------------------------------------------------------------
__global__ __launch_bounds__(64) void attn3_k(const ushort* __restrict__ qkvb,
                                              const ushort* __restrict__ vt,
                                              float* __restrict__ po0,
                                              float* __restrict__ po1,
                                              float* __restrict__ pml)
{
    __shared__ ushort Ps[16][72];       // per-wave P transpose buffer

    const int q0   = blockIdx.x * 16;
    const int h    = blockIdx.y;
    const int sp   = blockIdx.z;        // kv split 0/1
    const int lane = threadIdx.x;
    const int g    = lane >> 4;         // 0..3
    const int c    = lane & 15;

    // Q A-fragments (pre-scaled in qkvb)
    const ushort* qp = qkvb + (size_t)(q0 + c) * 768 + h * 64;
    const bf16x8_t qf0 = *(const bf16x8_t*)(qp + g * 8);
    const bf16x8_t qf1 = *(const bf16x8_t*)(qp + g * 8 + 32);

    f32x4_t o[4];
    float m[4], l[4];
    #pragma unroll
    for (int r = 0; r < 4; ++r) {
        m[r] = -1e30f; l[r] = 0.f;
        o[r][0] = 0.f; o[r][1] = 0.f; o[r][2] = 0.f; o[r][3] = 0.f;
    }

    const ushort* kcol = qkvb + 256 + h * 64 + g * 8;    // + row*768 (+32 for ks=1)
    const ushort* vrow = vt + (size_t)(h * 64 + c) * 4096 + g * 8;  // + d0*16*4096 + kv0

    for (int kt = sp * 32; kt < sp * 32 + 32; ++kt) {
        const int kv0 = kt * 64;

        // --- S = Q K^T : K B-frags straight from global (L2) ---
        f32x4_t s[4];
        #pragma unroll
        for (int t = 0; t < 4; ++t) {
            const ushort* kr = kcol + (size_t)(kv0 + c + 16 * t) * 768;
            bf16x8_t b0 = *(const bf16x8_t*)(kr);
            bf16x8_t b1 = *(const bf16x8_t*)(kr + 32);
            f32x4_t a; a[0] = 0.f; a[1] = 0.f; a[2] = 0.f; a[3] = 0.f;
            a = __builtin_amdgcn_mfma_f32_16x16x32_bf16(qf0, b0, a, 0, 0, 0);
            a = __builtin_amdgcn_mfma_f32_16x16x32_bf16(qf1, b1, a, 0, 0, 0);
            s[t] = a;
        }

        // --- V fragments issued BEFORE softmax: exp/shfl VALU hides L2 latency ---
        bf16x8_t vf[4][2];
        #pragma unroll
        for (int d0 = 0; d0 < 4; ++d0) {
            const ushort* vr = vrow + (size_t)(16 * d0) * 4096 + kv0;
            vf[d0][0] = *(const bf16x8_t*)(vr);
            vf[d0][1] = *(const bf16x8_t*)(vr + 32);
        }

        // --- online softmax (rows g*4+r; 16 lanes share a row group) ---
        #pragma unroll
        for (int r = 0; r < 4; ++r) {
            float mx = fmaxf(fmaxf(s[0][r], s[1][r]), fmaxf(s[2][r], s[3][r]));
            mx = fmaxf(mx, __shfl_xor(mx, 1));
            mx = fmaxf(mx, __shfl_xor(mx, 2));
            mx = fmaxf(mx, __shfl_xor(mx, 4));
            mx = fmaxf(mx, __shfl_xor(mx, 8));
            float mn = fmaxf(m[r], mx);
            float alpha = __expf(m[r] - mn);
            m[r] = mn;
            float p0 = __expf(s[0][r] - mn);
            float p1 = __expf(s[1][r] - mn);
            float p2 = __expf(s[2][r] - mn);
            float p3 = __expf(s[3][r] - mn);
            float sum = p0 + p1 + p2 + p3;
            sum += __shfl_xor(sum, 1);
            sum += __shfl_xor(sum, 2);
            sum += __shfl_xor(sum, 4);
            sum += __shfl_xor(sum, 8);
            l[r] = l[r] * alpha + sum;
            o[0][r] *= alpha; o[1][r] *= alpha; o[2][r] *= alpha; o[3][r] *= alpha;
            ushort* pr = &Ps[g * 4 + r][c];
            pr[0]  = f2bf(p0);
            pr[16] = f2bf(p1);
            pr[32] = f2bf(p2);
            pr[48] = f2bf(p3);
        }
        // same-wave LDS RAW/WAR: compiler-inserted lgkmcnt (no barrier needed)

        // --- O += P @ V ---
        bf16x8_t pa0 = *(const bf16x8_t*)&Ps[c][g * 8];
        bf16x8_t pa1 = *(const bf16x8_t*)&Ps[c][g * 8 + 32];
        #pragma unroll
        for (int d0 = 0; d0 < 4; ++d0) {
            o[d0] = __builtin_amdgcn_mfma_f32_16x16x32_bf16(pa0, vf[d0][0], o[d0], 0, 0, 0);
            o[d0] = __builtin_amdgcn_mfma_f32_16x16x32_bf16(pa1, vf[d0][1], o[d0], 0, 0, 0);
        }
    }

    // --- write unnormalized partial O + (m, l) ---
    float* po = sp ? po1 : po0;         // [h][q][d] fp32
    #pragma unroll
    for (int r = 0; r < 4; ++r) {
        float* op = po + ((size_t)h * 4096 + q0 + g * 4 + r) * 64 + c;
        #pragma unroll
        for (int d0 = 0; d0 < 4; ++d0)
            op[16 * d0] = o[d0][r];
    }
    if (c == 0) {
        #pragma unroll
        for (int r = 0; r < 4; ++r) {
            size_t idx = ((size_t)(sp * 4 + h) * 4096 + q0 + g * 4 + r) * 2;
            pml[idx]     = m[r];
            pml[idx + 1] = l[r];
        }
    }
}

// ---------------------------------------------------------------------------
// Combine 2 KV-split partials -> normalized attn out, split bf16 [q][256].
// ---------------------------------------------------------------------------
__global__ __launch_bounds__(256) void comb_k(const float* __restrict__ po0,
                                              const float* __restrict__ po1,
                                              const float* __restrict__ pml,
                                              ushort* __restrict__ aoh,
                                              ushort* __restrict__ aol)
{
    int idx = blockIdx.x * 256 + threadIdx.x;     // over 4*4096*16
    int row = idx >> 4;                           // h*4096 + q
    int h = row >> 12, q = row & 4095;
    int dq = (idx & 15) * 4;
    const float* a = pml + ((size_t)(0 * 4 + h) * 4096 + q) * 2;
    const float* b = pml + ((size_t)(1 * 4 + h) * 4096 + q) * 2;
    float m1 = a[0], l1 = a[1], m2 = b[0], l2 = b[1];
    float mw = fmaxf(m1, m2);
    float a1 = __expf(m1 - mw), a2 = __expf(m2 - mw);
    float inv = 1.0f / (a1 * l1 + a2 * l2);
    float4 o1 = *(const float4*)(po0 + (size_t)row * 64 + dq);
    float4 o2 = *(const float4*)(po1 + (size_t)row * 64 + dq);
    float vx = (a1 * o1.x + a2 * o2.x) * inv;
    float vy = (a1 * o1.y + a2 * o2.y) * inv;
    float vz = (a1 * o1.z + a2 * o2.z) * inv;
    float vw = (a1 * o1.w + a2 * o2.w) * inv;
    size_t oi = (size_t)q * 256 + h * 64 + dq;
    ushort4 H, L;
    H.x = f2bf(vx); L.x = f2bf(vx - bf2f(H.x));
    H.y = f2bf(vy); L.y = f2bf(vy - bf2f(H.y));
    H.z = f2bf(vz); L.z = f2bf(vz - bf2f(H.z));
    H.w = f2bf(vw); L.w = f2bf(vw - bf2f(H.w));
    *(ushort4*)(aoh + oi) = H;
    *(ushort4*)(aol + oi) = L;
}

// ---------------------------------------------------------------------------
// Fused GCN aggregation on split operands (unchanged)
// ---------------------------------------------------------------------------
__global__ __launch_bounds__(128) void csr_agg2_k(const ushort* __restrict__ hh,
                                                  const ushort* __restrict__ hl,
                                                  const int* __restrict__ rowptr,
                                                  const int* __restrict__ ssrc,
                                                  const float* __restrict__ dinv,
                                                  const float* __restrict__ bias,
                                                  ushort* __restrict__ oh,
                                                  ushort* __restrict__ ol) {
    __shared__ int   nbr[64];
    __shared__ float wnb[64];
    const int d = blockIdx.x;
    const int c = threadIdx.x;
    const int beg = rowptr[d], end = rowptr[d + 1];

    float4 acc = {0.f, 0.f, 0.f, 0.f};
    for (int j0 = beg; j0 < end; j0 += 64) {
        const int mcnt = min(64, end - j0);
        if (c < mcnt) {
            int s = ssrc[j0 + c];
            nbr[c] = s;
            wnb[c] = dinv[s];
        }
        __syncthreads();
        for (int u = 0; u < mcnt; ++u) {
            const int s = nbr[u];
            const float w = wnb[u];
            ushort4 vh = *(const ushort4*)(hh + (size_t)s * 512 + c * 4);
            ushort4 vl = *(const ushort4*)(hl + (size_t)s * 512 + c * 4);
            acc.x += w * (bf2f(vh.x) + bf2f(vl.x));
            acc.y += w * (bf2f(vh.y) + bf2f(vl.y));
            acc.z += w * (bf2f(vh.z) + bf2f(vl.z));
            acc.w += w * (bf2f(vh.w) + bf2f(vl.w));
        }
        __syncthreads();
    }

    const float wd = dinv[d];
    const float wd2 = wd * wd;
    ushort4 sh = *(const ushort4*)(hh + (size_t)d * 512 + c * 4);
    ushort4 sl = *(const ushort4*)(hl + (size_t)d * 512 + c * 4);
    float4 bv = *((const float4*)bias + c);
    float r0 = fmaxf(acc.x * wd + wd2 * (bf2f(sh.x) + bf2f(sl.x)) + bv.x, 0.f);
    float r1 = fmaxf(acc.y * wd + wd2 * (bf2f(sh.y) + bf2f(sl.y)) + bv.y, 0.f);
    float r2 = fmaxf(acc.z * wd + wd2 * (bf2f(sh.z) + bf2f(sl.z)) + bv.z, 0.f);
    float r3 = fmaxf(acc.w * wd + wd2 * (bf2f(sh.w) + bf2f(sl.w)) + bv.w, 0.f);
    ushort4 H, L;
    H.x = f2bf(r0); L.x = f2bf(r0 - bf2f(H.x));
    H.y = f2bf(r1); L.y = f2bf(r1 - bf2f(H.y));
    H.z = f2bf(r2); L.z = f2bf(r2 - bf2f(H.z));
    H.w = f2bf(r3); L.w = f2bf(r3 - bf2f(H.w));
    *(ushort4*)(oh + (size_t)d * 512 + c * 4) = H;
    *(ushort4*)(ol + (size_t)d * 512 + c * 4) = L;
}

// ---------------------------------------------------------------------------
// Workspace ~23 MB. Attention partials time-share d_out (split 0) and the
// xt region (split 1) -- both dead until after comb_k.
// ---------------------------------------------------------------------------
extern "C" void kernel_launch(void* const* d_in, const int* in_sizes, int n_in,
                              void* d_out, int out_size, void* d_ws, size_t ws_size,
                              hipStream_t stream)
{
    const float* x          = (const float*)d_in[0];
    const int*   eidx       = (const int*)d_in[1];
    const float* gcn1_w     = (const float*)d_in[2];
    const float* gcn1_b     = (const float*)d_in[3];
    const float* gcn2_w     = (const float*)d_in[4];
    const float* gcn2_b     = (const float*)d_in[5];
    const float* lin_w      = (const float*)d_in[6];
    const float* lin_b      = (const float*)d_in[7];
    const float* in_proj_w  = (const float*)d_in[8];
    const float* in_proj_b  = (const float*)d_in[9];
    const float* out_proj_w = (const float*)d_in[10];
    const float* out_proj_b = (const float*)d_in[11];
    const float* proj_w     = (const float*)d_in[12];
    const float* proj_b     = (const float*)d_in[13];
    float* out = (float*)d_out;

    const int* esrc = eidx;
    const int* edst = eidx + NEDGE;

    char* base = (char*)d_ws;
    size_t off = 0;
    auto take = [&](size_t bytes) -> char* {
        char* p = base + off;
        off = (off + bytes + 255) & ~(size_t)255;
        return p;
    };

    int*   cnt    = (int*)take(N_NODES * 4);
    int*   tail   = (int*)take(N_NODES * 4);
    int*   rowptr = (int*)take((N_NODES + 8) * 4);
    int*   ssrc   = (int*)take(NEDGE * 4);
    float* dinv   = (float*)take(N_NODES * 4);
    float* pml    = (float*)take(2 * HEADS * N_NODES * 2 * 4);   // 256 KB

    // weight region (2 MB), time-shared transformer -> gcn
    ushort* wreg = (ushort*)take(2 * 1024 * 1024);
    ushort* ipW_h = wreg;
    ushort* ipW_l = ipW_h + 768 * 256;
    ushort* opW_h = ipW_l + 768 * 256;
    ushort* opW_l = opW_h + 256 * 256;
    ushort* pjT_h = opW_l + 256 * 256;
    ushort* pjT_l = pjT_h + 256 * 256;
    ushort* g1T_h = wreg;
    ushort* g1T_l = g1T_h + 512 * 256;
    ushort* g2T_h = g1T_l + 512 * 256;
    ushort* g2T_l = g2T_h + 512 * 512;
    ushort* lT_h  = g2T_l + 512 * 512;
    ushort* lT_l  = lT_h + 256 * 512;

    // xs (x split), 4 MB
    ushort* xs_h = (ushort*)take(N_NODES * IN_DIM * 2);
    ushort* xs_l = (ushort*)take(N_NODES * IN_DIM * 2);

    // R2 (8 MB): qkvb + vt  |  later GCN ping (Ph, Pl)
    char* R2 = take(8 * 1024 * 1024);
    ushort* qkvb = (ushort*)R2;
    ushort* vt   = qkvb + (size_t)N_NODES * 768;
    ushort* Ph   = (ushort*)R2;
    ushort* Pl   = Ph + (size_t)N_NODES * HIDDEN;

    // R3 (8 MB): ao split + xt split  |  attn partial 1 in xt |  GCN pong
    char* R3 = take(8 * 1024 * 1024);
    ushort* ao_h = (ushort*)R3;
    ushort* ao_l = ao_h + (size_t)N_NODES * IN_DIM;
    ushort* xt_h = ao_l + (size_t)N_NODES * IN_DIM;
    ushort* xt_l = xt_h + (size_t)N_NODES * IN_DIM;
    ushort* Qh   = (ushort*)R3;
    ushort* Ql   = Qh + (size_t)N_NODES * HIDDEN;

    float* po0 = out;            // 4 MB: [4][4096][64] fp32 (dead until proj)
    float* po1 = (float*)xt_h;   // 4 MB: xt region is dead until out_proj

    // --- CSR + dinv ---
    zero_i_k<<<(2 * N_NODES + 255) / 256, 256, 0, stream>>>(cnt, 2 * N_NODES);
    hist_k<<<(NEDGE + 255) / 256, 256, 0, stream>>>(edst, cnt);
    scan_k<<<1, 256, 0, stream>>>(cnt, rowptr, dinv);
    scatter_k<<<(NEDGE + 255) / 256, 256, 0, stream>>>(esrc, edst, rowptr, tail, ssrc);

    // --- input / transformer weight prep ---
    split_k<<<(N_NODES * IN_DIM / 4 + 255) / 256, 256, 0, stream>>>(x, xs_h, xs_l, N_NODES * IN_DIM / 4);
    split_k<<<(768 * 256 / 4 + 255) / 256, 256, 0, stream>>>(in_proj_w, ipW_h, ipW_l, 768 * 256 / 4);
    split_k<<<(256 * 256 / 4 + 255) / 256, 256, 0, stream>>>(out_proj_w, opW_h, opW_l, 256 * 256 / 4);
    tsplit_k<<<dim3(4, 4), 256, 0, stream>>>(proj_w, pjT_h, pjT_l, 256, 256);

    // --- transformer branch ---
    gemm_sp_k<4><<<dim3(64, 12), 256, 0, stream>>>(xs_h, xs_l, ipW_h, ipW_l,
        in_proj_b, nullptr, qkvb, nullptr, N_NODES, 768, 256);
    vtrans_k<<<dim3(64, 4), 256, 0, stream>>>(qkvb, vt);
    attn3_k<<<dim3(256, 4, 2), 64, 0, stream>>>(qkvb, vt, po0, po1, pml);
    comb_k<<<(HEADS * N_NODES * 16) / 256, 256, 0, stream>>>(po0, po1, pml, ao_h, ao_l);
    gemm_sp_k<2><<<dim3(64, 4), 256, 0, stream>>>(ao_h, ao_l, opW_h, opW_l,
        out_proj_b, nullptr, xt_h, xt_l, N_NODES, 256, 256);
    gemm_sp_k<0><<<dim3(64, 4), 256, 0, stream>>>(xt_h, xt_l, pjT_h, pjT_l,
        proj_b, nullptr, out, nullptr, N_NODES, 256, 256);

    // --- gcn weight prep (stream-ordered after transformer GEMMs) ---
    tsplit_k<<<dim3(4, 8), 256, 0, stream>>>(gcn1_w, g1T_h, g1T_l, 256, 512);
    tsplit_k<<<dim3(8, 8), 256, 0, stream>>>(gcn2_w, g2T_h, g2T_l, 512, 512);
    tsplit_k<<<dim3(8, 4), 256, 0, stream>>>(lin_w, lT_h, lT_l, 512, 256);

    // --- GCN branch ---
    gemm_sp_k<3><<<dim3(64, 8), 256, 0, stream>>>(xs_h, xs_l, g1T_h, g1T_l,
        nullptr, nullptr, Ph, Pl, N_NODES, HIDDEN, IN_DIM);
    csr_agg2_k<<<N_NODES, 128, 0, stream>>>(Ph, Pl, rowptr, ssrc, dinv, gcn1_b, Qh, Ql);
    gemm_sp_k<3><<<dim3(64, 8), 256, 0, stream>>>(Qh, Ql, g2T_h, g2T_l,
        nullptr, nullptr, Ph, Pl, N_NODES, HIDDEN, HIDDEN);
    csr_agg2_k<<<N_NODES, 128, 0, stream>>>(Ph, Pl, rowptr, ssrc, dinv, gcn2_b, Qh, Ql);

    // --- final: out = relu(h2 @ lin_w + lin_b + x_proj) ---
    gemm_sp_k<1><<<dim3(64, 4), 256, 0, stream>>>(Qh, Ql, lT_h, lT_l,
        lin_b, out, out, nullptr, N_NODES, CLASSES, HIDDEN);
}